// Round 6
// baseline (246.644 us; speedup 1.0000x reference)
//
#include <hip/hip_runtime.h>

#define NB 64
#define CH 128
#define NNODE 2048
#define NH 4
#define DKK 32
#define INVS 0.17677669529663687f

typedef __bf16 bf16x8 __attribute__((ext_vector_type(8)));
typedef float f32x4 __attribute__((ext_vector_type(4)));
typedef unsigned short ushort_t;

union U16x8 { uint4 u; bf16x8 b; unsigned short s[8]; };
union U16x4 { uint2 u; unsigned short s[4]; };

__device__ inline bf16x8 as_bf16x8(uint4 u){ U16x8 x; x.u = u; return x.b; }
__device__ inline unsigned short f2b(float f){ __bf16 h = (__bf16)f; return __builtin_bit_cast(unsigned short, h); }
__device__ inline float b2f(unsigned short u){ __bf16 h = __builtin_bit_cast(__bf16, u); return (float)h; }

// XT XOR swizzle: 16B-granular (8 u16), keyed on row bits 2-4. Bijective per
// row. Round-4 counters: 4.06M bank conflicts == staging-write count (8-way);
// this spreads the 16-rows x 4-colgroups write across 32 banks (2-way = free).
#define XT_IDX(n, c) ((n) * 136 + ((c) ^ ((((n) >> 2) & 7) << 3)))

// ---------------------------------------------------------------------------
// k0_prep: weights->bf16, key softmax -> keysT bf16 [h][x][n], zero bias_dyn,
// build bpT [32][2048]. grid 256 x 256  (gid < 65536)
// ---------------------------------------------------------------------------
__global__ __launch_bounds__(256) void k0_prep(const float* __restrict__ qw,
    const float* __restrict__ vw, const float* __restrict__ cw,
    const float* __restrict__ memory, const float* __restrict__ bias_pool,
    ushort_t* __restrict__ wqb, ushort_t* __restrict__ wvb, ushort_t* __restrict__ wcb,
    ushort_t* __restrict__ keysT, float* __restrict__ bias_dyn,
    ushort_t* __restrict__ bpT)
{
  int gid = blockIdx.x * 256 + threadIdx.x;
  if (gid < 16384) { wqb[gid] = f2b(qw[gid]); wvb[gid] = f2b(vw[gid]); wcb[gid] = f2b(cw[gid]); }
  bias_dyn[gid] = 0.f;                               // 2048*32 = 65536 == grid*block
  { int k = gid >> 11, m = gid & 2047;               // bpT[k][m] = bias_pool[m][k]
    bpT[gid] = f2b(bias_pool[m * 32 + k]); }
  if (gid < 8192) {  // one row (h,n) of 32: softmax(memory * invscale) -> keysT
    int h = gid >> 11, n = gid & 2047;
    const float* src = memory + (size_t)gid * 32;
    float v[32]; float m = -1e30f;
    #pragma unroll
    for (int i = 0; i < 32; ++i) { v[i] = src[i] * INVS; m = fmaxf(m, v[i]); }
    float s = 0.f;
    #pragma unroll
    for (int i = 0; i < 32; ++i) { v[i] = __expf(v[i] - m); s += v[i]; }
    float inv = 1.f / s;
    #pragma unroll
    for (int i = 0; i < 32; ++i)   // coalesced across n per instruction
      keysT[(size_t)(h * 32 + i) * 2048 + n] = f2b(v[i] * inv);
  }
}

// ---------------------------------------------------------------------------
// kb1: normalized softmax rows of relu(nv1@nv2) -> Ebuf bf16 [2048][2048]
// grid 2048 (one block per row n) x 256; fully coalesced nv2 reads
// ---------------------------------------------------------------------------
__global__ __launch_bounds__(256) void kb1(const float* __restrict__ nv1,
    const float* __restrict__ nv2, ushort_t* __restrict__ Ebuf)
{
  int n = blockIdx.x; int tid = threadIdx.x;
  float a1[10];
  #pragma unroll
  for (int d = 0; d < 10; ++d) a1[d] = nv1[n * 10 + d];
  int m0 = tid * 8;
  float s[8];
  #pragma unroll
  for (int j = 0; j < 8; ++j) s[j] = 0.f;
  #pragma unroll
  for (int d = 0; d < 10; ++d) {
    const float* p = nv2 + d * 2048 + m0;
    float4 u = *(const float4*)p; float4 v = *(const float4*)(p + 4);
    s[0] += a1[d] * u.x; s[1] += a1[d] * u.y; s[2] += a1[d] * u.z; s[3] += a1[d] * u.w;
    s[4] += a1[d] * v.x; s[5] += a1[d] * v.y; s[6] += a1[d] * v.z; s[7] += a1[d] * v.w;
  }
  float e[8]; float sum = 0.f;
  #pragma unroll
  for (int j = 0; j < 8; ++j) { e[j] = __expf(fmaxf(s[j], 0.f)); sum += e[j]; }
  #pragma unroll
  for (int d = 1; d < 64; d <<= 1) sum += __shfl_xor(sum, d);
  __shared__ float red[4];
  if ((tid & 63) == 0) red[tid >> 6] = sum;
  __syncthreads();
  float inv = 1.f / (red[0] + red[1] + red[2] + red[3]);
  U16x8 o;
  #pragma unroll
  for (int j = 0; j < 8; ++j) o.s[j] = f2b(e[j] * inv);
  *(uint4*)(Ebuf + (size_t)n * 2048 + m0) = o.u;
}

// ---------------------------------------------------------------------------
// kb2: bias_dyn = Ebuf @ bias_pool via MFMA. M=2048,N=32,K=2048, 8-way K-split
// grid 128 x 256; atomicAdd fp32 partials (bias_dyn zeroed by k0_prep)
// ---------------------------------------------------------------------------
__global__ __launch_bounds__(256) void kb2(const ushort_t* __restrict__ Ebuf,
    const ushort_t* __restrict__ bpT, float* __restrict__ bias_dyn)
{
  int bid = blockIdx.x;
  int n0 = (bid >> 3) * 128;
  int m0 = (bid & 7) * 256;
  int tid = threadIdx.x; int wv = tid >> 6; int lane = tid & 63;
  int quad = lane >> 4; int l16 = lane & 15;
  int r0 = n0 + 32 * wv;
  f32x4 zero4 = {0.f,0.f,0.f,0.f};
  f32x4 acc[2][2];
  acc[0][0] = zero4; acc[0][1] = zero4; acc[1][0] = zero4; acc[1][1] = zero4;
  for (int ks = 0; ks < 256; ks += 32) {
    int mb = m0 + ks + 8 * quad;
    bf16x8 a0 = *(const bf16x8*)(Ebuf + (size_t)(r0 + l16) * 2048 + mb);
    bf16x8 a1 = *(const bf16x8*)(Ebuf + (size_t)(r0 + 16 + l16) * 2048 + mb);
    bf16x8 b0 = *(const bf16x8*)(bpT + (size_t)l16 * 2048 + mb);
    bf16x8 b1 = *(const bf16x8*)(bpT + (size_t)(16 + l16) * 2048 + mb);
    acc[0][0] = __builtin_amdgcn_mfma_f32_16x16x32_bf16(a0, b0, acc[0][0], 0, 0, 0);
    acc[0][1] = __builtin_amdgcn_mfma_f32_16x16x32_bf16(a0, b1, acc[0][1], 0, 0, 0);
    acc[1][0] = __builtin_amdgcn_mfma_f32_16x16x32_bf16(a1, b0, acc[1][0], 0, 0, 0);
    acc[1][1] = __builtin_amdgcn_mfma_f32_16x16x32_bf16(a1, b1, acc[1][1], 0, 0, 0);
  }
  #pragma unroll
  for (int rt = 0; rt < 2; ++rt)
    #pragma unroll
    for (int ct = 0; ct < 2; ++ct)
      #pragma unroll
      for (int r = 0; r < 4; ++r)
        atomicAdd(bias_dyn + (size_t)(r0 + 16*rt + 4*quad + r) * 32 + 16*ct + l16,
                  acc[rt][ct][r]);
}

// ---------------------------------------------------------------------------
// k1_qv v5: merged single MFMA pass (Q+V accumulators together; round 3/4
// showed the remat was a VGPR-budget artifact — launch_bounds(256,4) gives a
// 128-VGPR budget and wq+wvw+accs+vout ~= 115 fits). XT XOR-swizzled (round 4:
// 4.06M bank conflicts == staging writes, 8-way). kv-partial tail with
// per-block stores (round 3 post-mortem: no atomics). grid 2048 x 256.
// ---------------------------------------------------------------------------
__global__ __launch_bounds__(256, 4) void k1_qv(const float* __restrict__ x,
    const ushort_t* __restrict__ wqb, const ushort_t* __restrict__ wvb,
    const float* __restrict__ qbias, const float* __restrict__ vbias,
    const ushort_t* __restrict__ keysT,
    ushort_t* __restrict__ QsT, ushort_t* __restrict__ VT,
    float* __restrict__ kvp)
{
  int bid = blockIdx.x; int b = bid >> 5; int n0 = (bid & 31) * 64;
  int tid = threadIdx.x; int wv = tid >> 6; int lane = tid & 63;
  int quad = lane >> 4; int l16 = lane & 15;
  __shared__ __align__(16) ushort_t XT[64 * 136];   // x^T bf16 (swizzled), later V out
  __shared__ __align__(16) ushort_t QO[64][136];    // Q out (conflict-free as-is)

  f32x4 zero4 = {0.f,0.f,0.f,0.f};

  // both weight-frag sets issued before staging so they're in flight during it
  uint4 wq[2][4], wvw[2][4];
  #pragma unroll
  for (int ct = 0; ct < 2; ++ct)
    #pragma unroll
    for (int k0 = 0; k0 < 4; ++k0) {
      int off = (32 * wv + 16 * ct + l16) * 128 + 32 * k0 + 8 * quad;
      wq[ct][k0]  = *(const uint4*)(wqb + off);
      wvw[ct][k0] = *(const uint4*)(wvb + off);
    }

  // stage x [128c][64n] fp32 -> XT[n][c] bf16 (swizzled); 4c x 4n per thread
  #pragma unroll
  for (int p = 0; p < 2; ++p) {
    int c4 = 4 * ((tid >> 4) + 16 * p);
    int n4 = 4 * (tid & 15);
    float4 r[4];
    #pragma unroll
    for (int j = 0; j < 4; ++j)
      r[j] = *(const float4*)(x + (size_t)(b * 128 + c4 + j) * 2048 + n0 + n4);
    #pragma unroll
    for (int i = 0; i < 4; ++i) {
      U16x4 w;
      w.s[0] = f2b(((const float*)&r[0])[i]);
      w.s[1] = f2b(((const float*)&r[1])[i]);
      w.s[2] = f2b(((const float*)&r[2])[i]);
      w.s[3] = f2b(((const float*)&r[3])[i]);
      *(uint2*)&XT[XT_IDX(n4 + i, c4)] = w.u;
    }
  }
  __syncthreads();

  float4 qb4[2], vb4[2];
  #pragma unroll
  for (int ct = 0; ct < 2; ++ct) {
    qb4[ct] = *(const float4*)(qbias + 32 * wv + 16 * ct + 4 * quad);
    vb4[ct] = *(const float4*)(vbias + 32 * wv + 16 * ct + 4 * quad);
  }

  uint2 vout[4][2];
  #pragma unroll
  for (int nt = 0; nt < 4; ++nt) {
    f32x4 aq[2];  aq[0] = zero4;  aq[1] = zero4;
    f32x4 avv[2]; avv[0] = zero4; avv[1] = zero4;
    #pragma unroll
    for (int k0 = 0; k0 < 4; ++k0) {
      bf16x8 bfrag = *(const bf16x8*)&XT[XT_IDX(16 * nt + l16, 32 * k0 + 8 * quad)];
      aq[0]  = __builtin_amdgcn_mfma_f32_16x16x32_bf16(as_bf16x8(wq[0][k0]),  bfrag, aq[0],  0, 0, 0);
      aq[1]  = __builtin_amdgcn_mfma_f32_16x16x32_bf16(as_bf16x8(wq[1][k0]),  bfrag, aq[1],  0, 0, 0);
      avv[0] = __builtin_amdgcn_mfma_f32_16x16x32_bf16(as_bf16x8(wvw[0][k0]), bfrag, avv[0], 0, 0, 0);
      avv[1] = __builtin_amdgcn_mfma_f32_16x16x32_bf16(as_bf16x8(wvw[1][k0]), bfrag, avv[1], 0, 0, 0);
    }
    // Q softmax over this head's 32 channels for node n = n0+16nt+l16.
    float sq[2][4]; float mx = -1e30f;
    #pragma unroll
    for (int ct = 0; ct < 2; ++ct)
      #pragma unroll
      for (int r = 0; r < 4; ++r) {
        sq[ct][r] = fmaxf(aq[ct][r] + ((const float*)&qb4[ct])[r], 0.f) * INVS;
        mx = fmaxf(mx, sq[ct][r]);
      }
    mx = fmaxf(mx, __shfl_xor(mx, 16));
    mx = fmaxf(mx, __shfl_xor(mx, 32));
    float sum = 0.f;
    #pragma unroll
    for (int ct = 0; ct < 2; ++ct)
      #pragma unroll
      for (int r = 0; r < 4; ++r) { sq[ct][r] = __expf(sq[ct][r] - mx); sum += sq[ct][r]; }
    sum += __shfl_xor(sum, 16);
    sum += __shfl_xor(sum, 32);
    float inv = 1.f / sum;
    #pragma unroll
    for (int ct = 0; ct < 2; ++ct) {
      U16x4 w;
      #pragma unroll
      for (int r = 0; r < 4; ++r) w.s[r] = f2b(sq[ct][r] * inv);
      *(uint2*)&QO[16 * nt + l16][32 * wv + 16 * ct + 4 * quad] = w.u;
    }
    // V = relu(+vb) packed bf16, held in registers until XT is free
    #pragma unroll
    for (int ct = 0; ct < 2; ++ct) {
      U16x4 w;
      #pragma unroll
      for (int r = 0; r < 4; ++r)
        w.s[r] = f2b(fmaxf(avv[ct][r] + ((const float*)&vb4[ct])[r], 0.f));
      vout[nt][ct] = w.u;
    }
  }
  __syncthreads();   // all XT x-reads done

  #pragma unroll
  for (int nt = 0; nt < 4; ++nt)
    #pragma unroll
    for (int ct = 0; ct < 2; ++ct)
      *(uint2*)&XT[XT_IDX(16 * nt + l16, 32 * wv + 16 * ct + 4 * quad)] = vout[nt][ct];
  __syncthreads();   // XT now holds V

  // ---- fused kv partial: wave wv = head. kv[x][y] += sum_n K[h][x][n]*V[n][32h+y]
  // plain per-block stores (NO atomics — round 3 post-mortem)
  {
    f32x4 akv[2][2];
    akv[0][0] = zero4; akv[0][1] = zero4; akv[1][0] = zero4; akv[1][1] = zero4;
    #pragma unroll
    for (int ks = 0; ks < 2; ++ks) {
      const ushort_t* kp = keysT + (size_t)(32 * wv) * 2048 + n0 + 32 * ks + 8 * quad;
      bf16x8 ka0 = *(const bf16x8*)(kp + (size_t)l16 * 2048);
      bf16x8 ka1 = *(const bf16x8*)(kp + (size_t)(16 + l16) * 2048);
      U16x8 v0, v1;
      #pragma unroll
      for (int j = 0; j < 8; ++j) {
        int rowk = 32 * ks + 8 * quad + j;
        v0.s[j] = XT[XT_IDX(rowk, 32 * wv + l16)];
        v1.s[j] = XT[XT_IDX(rowk, 32 * wv + 16 + l16)];
      }
      akv[0][0] = __builtin_amdgcn_mfma_f32_16x16x32_bf16(ka0, v0.b, akv[0][0], 0, 0, 0);
      akv[0][1] = __builtin_amdgcn_mfma_f32_16x16x32_bf16(ka0, v1.b, akv[0][1], 0, 0, 0);
      akv[1][0] = __builtin_amdgcn_mfma_f32_16x16x32_bf16(ka1, v0.b, akv[1][0], 0, 0, 0);
      akv[1][1] = __builtin_amdgcn_mfma_f32_16x16x32_bf16(ka1, v1.b, akv[1][1], 0, 0, 0);
    }
    float* kdst = kvp + (size_t)bid * 4096 + wv * 1024;   // [bid][h][y][x]
    #pragma unroll
    for (int xt = 0; xt < 2; ++xt)
      #pragma unroll
      for (int yt = 0; yt < 2; ++yt)
        #pragma unroll
        for (int r = 0; r < 4; ++r)
          kdst[(16 * yt + l16) * 32 + 16 * xt + 4 * quad + r] = akv[xt][yt][r];
  }

  // coalesced bf16 stores [b][n][128]
  #pragma unroll
  for (int j = 0; j < 4; ++j) {
    int id = tid + 256 * j; int n = id >> 4; int u = id & 15;
    size_t go = (size_t)(b * 2048 + n0 + n) * 128 + 8 * u;
    *(uint4*)(QsT + go) = *(uint4*)&QO[n][8 * u];
    *(uint4*)(VT  + go) = *(uint4*)&XT[XT_IDX(n, 8 * u)];
  }
}

// ---------------------------------------------------------------------------
// kred: kvws[b][i] = sum over 32 node-tile partials, float4 per thread.
// grid 256 x 256 (65536 float4 outputs), coalesced.
// ---------------------------------------------------------------------------
__global__ __launch_bounds__(256) void kred(const float* __restrict__ kvp,
    float* __restrict__ kvws)
{
  int gid = blockIdx.x * 256 + threadIdx.x;   // 65536 float4 outputs
  int b = gid >> 10; int i = gid & 1023;
  const float* p = kvp + (size_t)(b * 32) * 4096 + i * 4;
  float4 s = {0.f,0.f,0.f,0.f};
  #pragma unroll
  for (int t = 0; t < 32; ++t) {
    float4 v = *(const float4*)(p + (size_t)t * 4096);
    s.x += v.x; s.y += v.y; s.z += v.z; s.w += v.w;
  }
  *(float4*)(kvws + (size_t)gid * 4) = s;
}

// ---------------------------------------------------------------------------
// k3_out: attn_qkv (block-diag GEMM, K=32/head) + Ws*V + bias_dyn -> MID(LDS),
// then final conv GEMM + relu + affine residual. Block: 64 nodes of one b.
// Epilogue restages fp32 results through an LDS overlay (dead MID+VL region)
// for fully-coalesced float4 aff reads + out stores.
// grid 64*32 = 2048 x 256; wave w owns head w / c_out group w.
// ---------------------------------------------------------------------------
__global__ __launch_bounds__(256, 3) void k3_out(const ushort_t* __restrict__ QsT,
    const ushort_t* __restrict__ VT, const float* __restrict__ kvws,
    const float* __restrict__ bias_dyn, const ushort_t* __restrict__ wcb,
    const float* __restrict__ cbias, const float* __restrict__ wpool,
    const float* __restrict__ aff_w, const float* __restrict__ aff_b,
    float* __restrict__ out)
{
  int bid = blockIdx.x; int b = bid >> 5; int n0 = (bid & 31) * 64;
  int tid = threadIdx.x; int wv = tid >> 6; int lane = tid & 63;
  int quad = lane >> 4; int l16 = lane & 15;
  // manual carve so the fp32 output stage can overlay dead MID+VL:
  //   kvT  [4][32][40] u16   @ 0      (10240 B)
  //   MID  [64][136]   u16   @ 10240  (17408 B)
  //   VL   [64][132]   u16   @ 27648  (16896 B)
  //   BD   [64][36]    f32   @ 44544  ( 9216 B)   total 53760 -> 3 blocks/CU
  //   OST  [128][64]   f32   @ 10240  (32768 B)   overlay, after GEMM2
  __shared__ __align__(16) char smem[53760];
  ushort_t (*kvT)[32][40] = (ushort_t(*)[32][40])(smem);
  ushort_t (*MID)[136]    = (ushort_t(*)[136])(smem + 10240);
  ushort_t (*VL)[132]     = (ushort_t(*)[132])(smem + 27648);
  float    (*BD)[36]      = (float(*)[36])(smem + 44544);
  float    (*OST)[64]     = (float(*)[64])(smem + 10240);

  float Ws = 0.f;
  #pragma unroll
  for (int i = 0; i < 9; ++i) Ws += wpool[i];

  uint4 wc[2][4];
  #pragma unroll
  for (int mt = 0; mt < 2; ++mt)
    #pragma unroll
    for (int k0 = 0; k0 < 4; ++k0)
      wc[mt][k0] = *(const uint4*)(wcb + (32 * wv + 16 * mt + l16) * 128 + 32 * k0 + 8 * quad);

  #pragma unroll
  for (int p = 0; p < 16; ++p) {
    int id = tid + 256 * p;
    kvT[id >> 10][(id >> 5) & 31][id & 31] = f2b(kvws[(size_t)b * 4096 + id]);
  }
  #pragma unroll
  for (int p = 0; p < 4; ++p) {        // V tile: 64 rows x 128 cols bf16
    int id = tid + 256 * p; int n = id >> 4; int u = id & 15;
    *(uint4*)&VL[n][8 * u] = *(const uint4*)(VT + (size_t)(b * 2048 + n0 + n) * 128 + 8 * u);
  }
  #pragma unroll
  for (int p = 0; p < 2; ++p) {        // bias_dyn tile: 64 rows x 32
    int id = tid + 256 * p; int n = id >> 3; int g = id & 7;
    *(float4*)&BD[n][4 * g] = *(const float4*)(bias_dyn + (size_t)(n0 + n) * 32 + 4 * g);
  }
  __syncthreads();

  f32x4 zero4 = {0.f,0.f,0.f,0.f};
  f32x4 acc1[4][2];
  #pragma unroll
  for (int nt = 0; nt < 4; ++nt) { acc1[nt][0] = zero4; acc1[nt][1] = zero4; }
  #pragma unroll
  for (int nt = 0; nt < 4; ++nt) {
    bf16x8 aq = *(const bf16x8*)(QsT + (size_t)(b * 2048 + n0 + 16 * nt + l16) * 128 + 32 * wv + 8 * quad);
    #pragma unroll
    for (int ct = 0; ct < 2; ++ct)
      acc1[nt][ct] = __builtin_amdgcn_mfma_f32_16x16x32_bf16(
          aq, *(const bf16x8*)&kvT[wv][16 * ct + l16][8 * quad], acc1[nt][ct], 0, 0, 0);
  }

  // epilogue 1: MID = attn_qkv + Ws*V + bias_dyn (bf16 in LDS)
  #pragma unroll
  for (int nt = 0; nt < 4; ++nt)
    #pragma unroll
    for (int ct = 0; ct < 2; ++ct)
      #pragma unroll
      for (int r = 0; r < 4; ++r) {
        int nl = 16 * nt + 4 * quad + r;
        int cc = 32 * wv + 16 * ct + l16;
        float v = b2f(VL[nl][cc]);
        float bd = BD[nl][16 * ct + l16];
        MID[nl][cc] = f2b(acc1[nt][ct][r] + Ws * v + bd);
      }
  __syncthreads();

  f32x4 acc2[2][4];
  #pragma unroll
  for (int mt = 0; mt < 2; ++mt)
    #pragma unroll
    for (int nt = 0; nt < 4; ++nt) acc2[mt][nt] = zero4;
  #pragma unroll
  for (int k0 = 0; k0 < 4; ++k0) {
    bf16x8 bb[4];
    #pragma unroll
    for (int nt = 0; nt < 4; ++nt)
      bb[nt] = *(const bf16x8*)&MID[16 * nt + l16][32 * k0 + 8 * quad];
    #pragma unroll
    for (int mt = 0; mt < 2; ++mt)
      #pragma unroll
      for (int nt = 0; nt < 4; ++nt)
        acc2[mt][nt] = __builtin_amdgcn_mfma_f32_16x16x32_bf16(
            as_bf16x8(wc[mt][k0]), bb[nt], acc2[mt][nt], 0, 0, 0);
  }
  __syncthreads();   // MID reads done; OST may overwrite

  // epilogue 2a: relu(+cb) -> OST[c][n] fp32
  float4 cb4[2];
  #pragma unroll
  for (int mt = 0; mt < 2; ++mt)
    cb4[mt] = *(const float4*)(cbias + 32 * wv + 16 * mt + 4 * quad);
  #pragma unroll
  for (int mt = 0; mt < 2; ++mt)
    #pragma unroll
    for (int nt = 0; nt < 4; ++nt)
      #pragma unroll
      for (int r = 0; r < 4; ++r) {
        int c_out = 32 * wv + 16 * mt + 4 * quad + r;
        OST[c_out][16 * nt + l16] = fmaxf(acc2[mt][nt][r] + ((const float*)&cb4[mt])[r], 0.f);
      }
  __syncthreads();

  // epilogue 2b: coalesced float4 aff reads + out stores
  #pragma unroll
  for (int p = 0; p < 8; ++p) {
    int id = tid + 256 * p; int c = id >> 4; int g = id & 15;
    float4 y = *(const float4*)&OST[c][4 * g];
    size_t ai = (size_t)c * 2048 + n0 + 4 * g;
    float4 aw4 = *(const float4*)(aff_w + ai);
    float4 ab4 = *(const float4*)(aff_b + ai);
    float4 o;
    o.x = y.x * aw4.x + ab4.x + y.x;
    o.y = y.y * aw4.y + ab4.y + y.y;
    o.z = y.z * aw4.z + ab4.z + y.z;
    o.w = y.w * aw4.w + ab4.w + y.w;
    *(float4*)(out + (size_t)(b * 128 + c) * 2048 + n0 + 4 * g) = o;
  }
}

// ---------------------------------------------------------------------------
extern "C" void kernel_launch(void* const* d_in, const int* in_sizes, int n_in,
                              void* d_out, int out_size, void* d_ws, size_t ws_size,
                              hipStream_t stream)
{
  const float* x      = (const float*)d_in[0];
  const float* qw     = (const float*)d_in[1];
  const float* qb     = (const float*)d_in[2];
  const float* vw     = (const float*)d_in[3];
  const float* vb     = (const float*)d_in[4];
  const float* cw     = (const float*)d_in[5];
  const float* cb     = (const float*)d_in[6];
  const float* memory = (const float*)d_in[7];
  const float* nv1    = (const float*)d_in[8];
  const float* nv2    = (const float*)d_in[9];
  const float* wpool  = (const float*)d_in[10];
  const float* bpool  = (const float*)d_in[11];
  const float* aw     = (const float*)d_in[12];
  const float* ab     = (const float*)d_in[13];
  float* out = (float*)d_out;

  char* ws = (char*)d_ws;
  ushort_t* QsT      = (ushort_t*)(ws);                 // 33,554,432 B
  ushort_t* VT       = (ushort_t*)(ws + 33554432);      // 33,554,432 B
  float*    kvws     = (float*)   (ws + 67108864);      //  1,048,576 B
  ushort_t* keysT    = (ushort_t*)(ws + 68157440);      //    524,288 B
  float*    bias_dyn = (float*)   (ws + 69206016);      //    262,144 B
  ushort_t* wqb      = (ushort_t*)(ws + 69468160);      //     32,768 B
  ushort_t* wvb      = (ushort_t*)(ws + 69500928);      //     32,768 B
  ushort_t* wcb      = (ushort_t*)(ws + 69533696);      //     32,768 B
  ushort_t* Ebuf     = (ushort_t*)(ws + 69566464);      //  8,388,608 B (end 77,955,072)
  ushort_t* bpT      = (ushort_t*)(ws + 77955072);      //    131,072 B (end 78,086,144)
  float*    kvp      = (float*)   (ws + 78086144);      // 33,554,432 B (end 111,640,576)

  k0_prep<<<256, 256, 0, stream>>>(qw, vw, cw, memory, bpool, wqb, wvb, wcb,
                                   keysT, bias_dyn, bpT);
  kb1<<<2048, 256, 0, stream>>>(nv1, nv2, Ebuf);
  kb2<<<128, 256, 0, stream>>>(Ebuf, bpT, bias_dyn);
  k1_qv<<<2048, 256, 0, stream>>>(x, wqb, wvb, qb, vb, keysT, QsT, VT, kvp);
  kred<<<256, 256, 0, stream>>>(kvp, kvws);
  k3_out<<<2048, 256, 0, stream>>>(QsT, VT, kvws, bias_dyn, wcb, cb, wpool, aw, ab, out);
}

// Round 7
// 215.851 us; speedup vs baseline: 1.1427x; 1.1427x over previous
//
#include <hip/hip_runtime.h>

#define NB 64
#define CH 128
#define NNODE 2048
#define NH 4
#define DKK 32
#define INVS 0.17677669529663687f

typedef __bf16 bf16x8 __attribute__((ext_vector_type(8)));
typedef float f32x4 __attribute__((ext_vector_type(4)));
typedef unsigned short ushort_t;

union U16x8 { uint4 u; bf16x8 b; unsigned short s[8]; };
union U16x4 { uint2 u; unsigned short s[4]; };

__device__ inline bf16x8 as_bf16x8(uint4 u){ U16x8 x; x.u = u; return x.b; }
__device__ inline unsigned short f2b(float f){ __bf16 h = (__bf16)f; return __builtin_bit_cast(unsigned short, h); }
__device__ inline float b2f(unsigned short u){ __bf16 h = __builtin_bit_cast(__bf16, u); return (float)h; }

// XT XOR swizzle: 16B-granular (8 u16), keyed on row bits 2-4. Bijective per
// row; XOR values are multiples of 8 so all uint2/uint4/b128 accesses stay
// aligned. Validated r6: staging-write conflicts 4.06M -> 1.84M, refcheck OK.
#define XT_IDX(n, c) ((n) * 136 + ((c) ^ ((((n) >> 2) & 7) << 3)))

// ---------------------------------------------------------------------------
// k0_prep: weights->bf16, key softmax -> keysT bf16 [h][x][n], zero bias_dyn,
// build bpT [32][2048]. grid 256 x 256  (gid < 65536)
// ---------------------------------------------------------------------------
__global__ __launch_bounds__(256) void k0_prep(const float* __restrict__ qw,
    const float* __restrict__ vw, const float* __restrict__ cw,
    const float* __restrict__ memory, const float* __restrict__ bias_pool,
    ushort_t* __restrict__ wqb, ushort_t* __restrict__ wvb, ushort_t* __restrict__ wcb,
    ushort_t* __restrict__ keysT, float* __restrict__ bias_dyn,
    ushort_t* __restrict__ bpT)
{
  int gid = blockIdx.x * 256 + threadIdx.x;
  if (gid < 16384) { wqb[gid] = f2b(qw[gid]); wvb[gid] = f2b(vw[gid]); wcb[gid] = f2b(cw[gid]); }
  bias_dyn[gid] = 0.f;                               // 2048*32 = 65536 == grid*block
  { int k = gid >> 11, m = gid & 2047;               // bpT[k][m] = bias_pool[m][k]
    bpT[gid] = f2b(bias_pool[m * 32 + k]); }
  if (gid < 8192) {  // one row (h,n) of 32: softmax(memory * invscale) -> keysT
    int h = gid >> 11, n = gid & 2047;
    const float* src = memory + (size_t)gid * 32;
    float v[32]; float m = -1e30f;
    #pragma unroll
    for (int i = 0; i < 32; ++i) { v[i] = src[i] * INVS; m = fmaxf(m, v[i]); }
    float s = 0.f;
    #pragma unroll
    for (int i = 0; i < 32; ++i) { v[i] = __expf(v[i] - m); s += v[i]; }
    float inv = 1.f / s;
    #pragma unroll
    for (int i = 0; i < 32; ++i)   // coalesced across n per instruction
      keysT[(size_t)(h * 32 + i) * 2048 + n] = f2b(v[i] * inv);
  }
}

// ---------------------------------------------------------------------------
// kb1: normalized softmax rows of relu(nv1@nv2) -> Ebuf bf16 [2048][2048]
// grid 2048 (one block per row n) x 256; fully coalesced nv2 reads
// ---------------------------------------------------------------------------
__global__ __launch_bounds__(256) void kb1(const float* __restrict__ nv1,
    const float* __restrict__ nv2, ushort_t* __restrict__ Ebuf)
{
  int n = blockIdx.x; int tid = threadIdx.x;
  float a1[10];
  #pragma unroll
  for (int d = 0; d < 10; ++d) a1[d] = nv1[n * 10 + d];
  int m0 = tid * 8;
  float s[8];
  #pragma unroll
  for (int j = 0; j < 8; ++j) s[j] = 0.f;
  #pragma unroll
  for (int d = 0; d < 10; ++d) {
    const float* p = nv2 + d * 2048 + m0;
    float4 u = *(const float4*)p; float4 v = *(const float4*)(p + 4);
    s[0] += a1[d] * u.x; s[1] += a1[d] * u.y; s[2] += a1[d] * u.z; s[3] += a1[d] * u.w;
    s[4] += a1[d] * v.x; s[5] += a1[d] * v.y; s[6] += a1[d] * v.z; s[7] += a1[d] * v.w;
  }
  float e[8]; float sum = 0.f;
  #pragma unroll
  for (int j = 0; j < 8; ++j) { e[j] = __expf(fmaxf(s[j], 0.f)); sum += e[j]; }
  #pragma unroll
  for (int d = 1; d < 64; d <<= 1) sum += __shfl_xor(sum, d);
  __shared__ float red[4];
  if ((tid & 63) == 0) red[tid >> 6] = sum;
  __syncthreads();
  float inv = 1.f / (red[0] + red[1] + red[2] + red[3]);
  U16x8 o;
  #pragma unroll
  for (int j = 0; j < 8; ++j) o.s[j] = f2b(e[j] * inv);
  *(uint4*)(Ebuf + (size_t)n * 2048 + m0) = o.u;
}

// ---------------------------------------------------------------------------
// kb2: bias_dyn = Ebuf @ bias_pool via MFMA. M=2048,N=32,K=2048, 8-way K-split
// grid 128 x 256; atomicAdd fp32 partials (bias_dyn zeroed by k0_prep)
// ---------------------------------------------------------------------------
__global__ __launch_bounds__(256) void kb2(const ushort_t* __restrict__ Ebuf,
    const ushort_t* __restrict__ bpT, float* __restrict__ bias_dyn)
{
  int bid = blockIdx.x;
  int n0 = (bid >> 3) * 128;
  int m0 = (bid & 7) * 256;
  int tid = threadIdx.x; int wv = tid >> 6; int lane = tid & 63;
  int quad = lane >> 4; int l16 = lane & 15;
  int r0 = n0 + 32 * wv;
  f32x4 zero4 = {0.f,0.f,0.f,0.f};
  f32x4 acc[2][2];
  acc[0][0] = zero4; acc[0][1] = zero4; acc[1][0] = zero4; acc[1][1] = zero4;
  for (int ks = 0; ks < 256; ks += 32) {
    int mb = m0 + ks + 8 * quad;
    bf16x8 a0 = *(const bf16x8*)(Ebuf + (size_t)(r0 + l16) * 2048 + mb);
    bf16x8 a1 = *(const bf16x8*)(Ebuf + (size_t)(r0 + 16 + l16) * 2048 + mb);
    bf16x8 b0 = *(const bf16x8*)(bpT + (size_t)l16 * 2048 + mb);
    bf16x8 b1 = *(const bf16x8*)(bpT + (size_t)(16 + l16) * 2048 + mb);
    acc[0][0] = __builtin_amdgcn_mfma_f32_16x16x32_bf16(a0, b0, acc[0][0], 0, 0, 0);
    acc[0][1] = __builtin_amdgcn_mfma_f32_16x16x32_bf16(a0, b1, acc[0][1], 0, 0, 0);
    acc[1][0] = __builtin_amdgcn_mfma_f32_16x16x32_bf16(a1, b0, acc[1][0], 0, 0, 0);
    acc[1][1] = __builtin_amdgcn_mfma_f32_16x16x32_bf16(a1, b1, acc[1][1], 0, 0, 0);
  }
  #pragma unroll
  for (int rt = 0; rt < 2; ++rt)
    #pragma unroll
    for (int ct = 0; ct < 2; ++ct)
      #pragma unroll
      for (int r = 0; r < 4; ++r)
        atomicAdd(bias_dyn + (size_t)(r0 + 16*rt + 4*quad + r) * 32 + 16*ct + l16,
                  acc[rt][ct][r]);
}

// ---------------------------------------------------------------------------
// k1_qv v7: two-pass (Q then V) MFMA — r4/r6 A/B proved the compiler spills
// the merged 2x-weight working set (r6: VGPR 64 + 117 MB scratch traffic).
// XT XOR-swizzled (r6: conflicts 4.06M -> 1.84M, refcheck OK). Fused kv tail
// with per-block partial stores (r3: atomics were the poison). grid 2048x256.
// ---------------------------------------------------------------------------
__global__ __launch_bounds__(256, 4) void k1_qv(const float* __restrict__ x,
    const ushort_t* __restrict__ wqb, const ushort_t* __restrict__ wvb,
    const float* __restrict__ qbias, const float* __restrict__ vbias,
    const ushort_t* __restrict__ keysT,
    ushort_t* __restrict__ QsT, ushort_t* __restrict__ VT,
    float* __restrict__ kvp)
{
  int bid = blockIdx.x; int b = bid >> 5; int n0 = (bid & 31) * 64;
  int tid = threadIdx.x; int wv = tid >> 6; int lane = tid & 63;
  int quad = lane >> 4; int l16 = lane & 15;
  __shared__ __align__(16) ushort_t XT[64 * 136];   // x^T bf16 (swizzled), later V out
  __shared__ __align__(16) ushort_t QO[64][136];    // Q out

  f32x4 zero4 = {0.f,0.f,0.f,0.f};

  // Q-pass weight frags issued before staging so they're in flight during it.
  uint4 wq[2][4];
  #pragma unroll
  for (int ct = 0; ct < 2; ++ct)
    #pragma unroll
    for (int k0 = 0; k0 < 4; ++k0)
      wq[ct][k0] = *(const uint4*)(wqb + (32 * wv + 16 * ct + l16) * 128 + 32 * k0 + 8 * quad);

  // stage x [128c][64n] fp32 -> XT[n][c] bf16 (swizzled); 4c x 4n per thread
  #pragma unroll
  for (int p = 0; p < 2; ++p) {
    int c4 = 4 * ((tid >> 4) + 16 * p);
    int n4 = 4 * (tid & 15);
    float4 r[4];
    #pragma unroll
    for (int j = 0; j < 4; ++j)
      r[j] = *(const float4*)(x + (size_t)(b * 128 + c4 + j) * 2048 + n0 + n4);
    #pragma unroll
    for (int i = 0; i < 4; ++i) {
      U16x4 w;
      w.s[0] = f2b(((const float*)&r[0])[i]);
      w.s[1] = f2b(((const float*)&r[1])[i]);
      w.s[2] = f2b(((const float*)&r[2])[i]);
      w.s[3] = f2b(((const float*)&r[3])[i]);
      *(uint2*)&XT[XT_IDX(n4 + i, c4)] = w.u;
    }
  }
  __syncthreads();

  // ---- PASS 1: Q = softmax(relu(Wq x + qb) / s) -> QO ----
  {
    float4 qb4[2];
    #pragma unroll
    for (int ct = 0; ct < 2; ++ct)
      qb4[ct] = *(const float4*)(qbias + 32 * wv + 16 * ct + 4 * quad);
    #pragma unroll
    for (int nt = 0; nt < 4; ++nt) {
      f32x4 aq[2]; aq[0] = zero4; aq[1] = zero4;
      #pragma unroll
      for (int k0 = 0; k0 < 4; ++k0) {
        bf16x8 bfrag = *(const bf16x8*)&XT[XT_IDX(16 * nt + l16, 32 * k0 + 8 * quad)];
        aq[0] = __builtin_amdgcn_mfma_f32_16x16x32_bf16(as_bf16x8(wq[0][k0]), bfrag, aq[0], 0, 0, 0);
        aq[1] = __builtin_amdgcn_mfma_f32_16x16x32_bf16(as_bf16x8(wq[1][k0]), bfrag, aq[1], 0, 0, 0);
      }
      // softmax over this head's 32 channels for node n = n0+16nt+l16.
      float sq[2][4]; float mx = -1e30f;
      #pragma unroll
      for (int ct = 0; ct < 2; ++ct)
        #pragma unroll
        for (int r = 0; r < 4; ++r) {
          sq[ct][r] = fmaxf(aq[ct][r] + ((const float*)&qb4[ct])[r], 0.f) * INVS;
          mx = fmaxf(mx, sq[ct][r]);
        }
      mx = fmaxf(mx, __shfl_xor(mx, 16));
      mx = fmaxf(mx, __shfl_xor(mx, 32));
      float sum = 0.f;
      #pragma unroll
      for (int ct = 0; ct < 2; ++ct)
        #pragma unroll
        for (int r = 0; r < 4; ++r) { sq[ct][r] = __expf(sq[ct][r] - mx); sum += sq[ct][r]; }
      sum += __shfl_xor(sum, 16);
      sum += __shfl_xor(sum, 32);
      float inv = 1.f / sum;
      #pragma unroll
      for (int ct = 0; ct < 2; ++ct) {
        U16x4 w;
        #pragma unroll
        for (int r = 0; r < 4; ++r) w.s[r] = f2b(sq[ct][r] * inv);
        *(uint2*)&QO[16 * nt + l16][32 * wv + 16 * ct + 4 * quad] = w.u;
      }
    }
  }

  // ---- PASS 2: V = relu(Wv x + vb), packed to bf16 in-register ----
  uint2 vout[4][2];
  {
    uint4 wvw[2][4];
    #pragma unroll
    for (int ct = 0; ct < 2; ++ct)
      #pragma unroll
      for (int k0 = 0; k0 < 4; ++k0)
        wvw[ct][k0] = *(const uint4*)(wvb + (32 * wv + 16 * ct + l16) * 128 + 32 * k0 + 8 * quad);
    float4 vb4[2];
    #pragma unroll
    for (int ct = 0; ct < 2; ++ct)
      vb4[ct] = *(const float4*)(vbias + 32 * wv + 16 * ct + 4 * quad);
    #pragma unroll
    for (int nt = 0; nt < 4; ++nt) {
      f32x4 av[2]; av[0] = zero4; av[1] = zero4;
      #pragma unroll
      for (int k0 = 0; k0 < 4; ++k0) {
        bf16x8 bfrag = *(const bf16x8*)&XT[XT_IDX(16 * nt + l16, 32 * k0 + 8 * quad)];
        av[0] = __builtin_amdgcn_mfma_f32_16x16x32_bf16(as_bf16x8(wvw[0][k0]), bfrag, av[0], 0, 0, 0);
        av[1] = __builtin_amdgcn_mfma_f32_16x16x32_bf16(as_bf16x8(wvw[1][k0]), bfrag, av[1], 0, 0, 0);
      }
      #pragma unroll
      for (int ct = 0; ct < 2; ++ct) {
        U16x4 w;
        #pragma unroll
        for (int r = 0; r < 4; ++r)
          w.s[r] = f2b(fmaxf(av[ct][r] + ((const float*)&vb4[ct])[r], 0.f));
        vout[nt][ct] = w.u;
      }
    }
  }
  __syncthreads();   // all XT x-reads done

  #pragma unroll
  for (int nt = 0; nt < 4; ++nt)
    #pragma unroll
    for (int ct = 0; ct < 2; ++ct)
      *(uint2*)&XT[XT_IDX(16 * nt + l16, 32 * wv + 16 * ct + 4 * quad)] = vout[nt][ct];
  __syncthreads();   // XT now holds V

  // ---- fused kv partial: wave wv = head. kv[x][y] += sum_n K[h][x][n]*V[n][32h+y]
  // plain per-block stores (NO atomics — round 3 post-mortem)
  {
    f32x4 akv[2][2];
    akv[0][0] = zero4; akv[0][1] = zero4; akv[1][0] = zero4; akv[1][1] = zero4;
    #pragma unroll
    for (int ks = 0; ks < 2; ++ks) {
      const ushort_t* kp = keysT + (size_t)(32 * wv) * 2048 + n0 + 32 * ks + 8 * quad;
      bf16x8 ka0 = *(const bf16x8*)(kp + (size_t)l16 * 2048);
      bf16x8 ka1 = *(const bf16x8*)(kp + (size_t)(16 + l16) * 2048);
      U16x8 v0, v1;
      #pragma unroll
      for (int j = 0; j < 8; ++j) {
        int rowk = 32 * ks + 8 * quad + j;
        v0.s[j] = XT[XT_IDX(rowk, 32 * wv + l16)];
        v1.s[j] = XT[XT_IDX(rowk, 32 * wv + 16 + l16)];
      }
      akv[0][0] = __builtin_amdgcn_mfma_f32_16x16x32_bf16(ka0, v0.b, akv[0][0], 0, 0, 0);
      akv[0][1] = __builtin_amdgcn_mfma_f32_16x16x32_bf16(ka0, v1.b, akv[0][1], 0, 0, 0);
      akv[1][0] = __builtin_amdgcn_mfma_f32_16x16x32_bf16(ka1, v0.b, akv[1][0], 0, 0, 0);
      akv[1][1] = __builtin_amdgcn_mfma_f32_16x16x32_bf16(ka1, v1.b, akv[1][1], 0, 0, 0);
    }
    float* kdst = kvp + (size_t)bid * 4096 + wv * 1024;   // [bid][h][y][x]
    #pragma unroll
    for (int xt = 0; xt < 2; ++xt)
      #pragma unroll
      for (int yt = 0; yt < 2; ++yt)
        #pragma unroll
        for (int r = 0; r < 4; ++r)
          kdst[(16 * yt + l16) * 32 + 16 * xt + 4 * quad + r] = akv[xt][yt][r];
  }

  // coalesced bf16 stores [b][n][128]
  #pragma unroll
  for (int j = 0; j < 4; ++j) {
    int id = tid + 256 * j; int n = id >> 4; int u = id & 15;
    size_t go = (size_t)(b * 2048 + n0 + n) * 128 + 8 * u;
    *(uint4*)(QsT + go) = *(uint4*)&QO[n][8 * u];
    *(uint4*)(VT  + go) = *(uint4*)&XT[XT_IDX(n, 8 * u)];
  }
}

// ---------------------------------------------------------------------------
// kred: kvws[b][i] = sum over 32 node-tile partials, float4 per thread.
// grid 256 x 256 (65536 float4 outputs), coalesced.
// ---------------------------------------------------------------------------
__global__ __launch_bounds__(256) void kred(const float* __restrict__ kvp,
    float* __restrict__ kvws)
{
  int gid = blockIdx.x * 256 + threadIdx.x;   // 65536 float4 outputs
  int b = gid >> 10; int i = gid & 1023;
  const float* p = kvp + (size_t)(b * 32) * 4096 + i * 4;
  float4 s = {0.f,0.f,0.f,0.f};
  #pragma unroll
  for (int t = 0; t < 32; ++t) {
    float4 v = *(const float4*)(p + (size_t)t * 4096);
    s.x += v.x; s.y += v.y; s.z += v.z; s.w += v.w;
  }
  *(float4*)(kvws + (size_t)gid * 4) = s;
}

// ---------------------------------------------------------------------------
// k3_out: attn_qkv (block-diag GEMM, K=32/head) + Ws*V + bias_dyn -> MID(LDS),
// then final conv GEMM + relu + affine residual. Block: 64 nodes of one b.
// Epilogue restages fp32 results through an LDS overlay (dead MID+VL region)
// for fully-coalesced float4 aff reads + out stores.
// grid 64*32 = 2048 x 256; wave w owns head w / c_out group w.
// ---------------------------------------------------------------------------
__global__ __launch_bounds__(256, 3) void k3_out(const ushort_t* __restrict__ QsT,
    const ushort_t* __restrict__ VT, const float* __restrict__ kvws,
    const float* __restrict__ bias_dyn, const ushort_t* __restrict__ wcb,
    const float* __restrict__ cbias, const float* __restrict__ wpool,
    const float* __restrict__ aff_w, const float* __restrict__ aff_b,
    float* __restrict__ out)
{
  int bid = blockIdx.x; int b = bid >> 5; int n0 = (bid & 31) * 64;
  int tid = threadIdx.x; int wv = tid >> 6; int lane = tid & 63;
  int quad = lane >> 4; int l16 = lane & 15;
  // manual carve so the fp32 output stage can overlay dead MID+VL:
  //   kvT  [4][32][40] u16   @ 0      (10240 B)
  //   MID  [64][136]   u16   @ 10240  (17408 B)
  //   VL   [64][132]   u16   @ 27648  (16896 B)
  //   BD   [64][36]    f32   @ 44544  ( 9216 B)   total 53760 -> 3 blocks/CU
  //   OST  [128][64]   f32   @ 10240  (32768 B)   overlay, after GEMM2
  __shared__ __align__(16) char smem[53760];
  ushort_t (*kvT)[32][40] = (ushort_t(*)[32][40])(smem);
  ushort_t (*MID)[136]    = (ushort_t(*)[136])(smem + 10240);
  ushort_t (*VL)[132]     = (ushort_t(*)[132])(smem + 27648);
  float    (*BD)[36]      = (float(*)[36])(smem + 44544);
  float    (*OST)[64]     = (float(*)[64])(smem + 10240);

  float Ws = 0.f;
  #pragma unroll
  for (int i = 0; i < 9; ++i) Ws += wpool[i];

  uint4 wc[2][4];
  #pragma unroll
  for (int mt = 0; mt < 2; ++mt)
    #pragma unroll
    for (int k0 = 0; k0 < 4; ++k0)
      wc[mt][k0] = *(const uint4*)(wcb + (32 * wv + 16 * mt + l16) * 128 + 32 * k0 + 8 * quad);

  #pragma unroll
  for (int p = 0; p < 16; ++p) {
    int id = tid + 256 * p;
    kvT[id >> 10][(id >> 5) & 31][id & 31] = f2b(kvws[(size_t)b * 4096 + id]);
  }
  #pragma unroll
  for (int p = 0; p < 4; ++p) {        // V tile: 64 rows x 128 cols bf16
    int id = tid + 256 * p; int n = id >> 4; int u = id & 15;
    *(uint4*)&VL[n][8 * u] = *(const uint4*)(VT + (size_t)(b * 2048 + n0 + n) * 128 + 8 * u);
  }
  #pragma unroll
  for (int p = 0; p < 2; ++p) {        // bias_dyn tile: 64 rows x 32
    int id = tid + 256 * p; int n = id >> 3; int g = id & 7;
    *(float4*)&BD[n][4 * g] = *(const float4*)(bias_dyn + (size_t)(n0 + n) * 32 + 4 * g);
  }
  __syncthreads();

  f32x4 zero4 = {0.f,0.f,0.f,0.f};
  f32x4 acc1[4][2];
  #pragma unroll
  for (int nt = 0; nt < 4; ++nt) { acc1[nt][0] = zero4; acc1[nt][1] = zero4; }
  #pragma unroll
  for (int nt = 0; nt < 4; ++nt) {
    bf16x8 aq = *(const bf16x8*)(QsT + (size_t)(b * 2048 + n0 + 16 * nt + l16) * 128 + 32 * wv + 8 * quad);
    #pragma unroll
    for (int ct = 0; ct < 2; ++ct)
      acc1[nt][ct] = __builtin_amdgcn_mfma_f32_16x16x32_bf16(
          aq, *(const bf16x8*)&kvT[wv][16 * ct + l16][8 * quad], acc1[nt][ct], 0, 0, 0);
  }

  // epilogue 1: MID = attn_qkv + Ws*V + bias_dyn (bf16 in LDS)
  #pragma unroll
  for (int nt = 0; nt < 4; ++nt)
    #pragma unroll
    for (int ct = 0; ct < 2; ++ct)
      #pragma unroll
      for (int r = 0; r < 4; ++r) {
        int nl = 16 * nt + 4 * quad + r;
        int cc = 32 * wv + 16 * ct + l16;
        float v = b2f(VL[nl][cc]);
        float bd = BD[nl][16 * ct + l16];
        MID[nl][cc] = f2b(acc1[nt][ct][r] + Ws * v + bd);
      }
  __syncthreads();

  f32x4 acc2[2][4];
  #pragma unroll
  for (int mt = 0; mt < 2; ++mt)
    #pragma unroll
    for (int nt = 0; nt < 4; ++nt) acc2[mt][nt] = zero4;
  #pragma unroll
  for (int k0 = 0; k0 < 4; ++k0) {
    bf16x8 bb[4];
    #pragma unroll
    for (int nt = 0; nt < 4; ++nt)
      bb[nt] = *(const bf16x8*)&MID[16 * nt + l16][32 * k0 + 8 * quad];
    #pragma unroll
    for (int mt = 0; mt < 2; ++mt)
      #pragma unroll
      for (int nt = 0; nt < 4; ++nt)
        acc2[mt][nt] = __builtin_amdgcn_mfma_f32_16x16x32_bf16(
            as_bf16x8(wc[mt][k0]), bb[nt], acc2[mt][nt], 0, 0, 0);
  }
  __syncthreads();   // MID reads done; OST may overwrite

  // epilogue 2a: relu(+cb) -> OST[c][n] fp32
  float4 cb4[2];
  #pragma unroll
  for (int mt = 0; mt < 2; ++mt)
    cb4[mt] = *(const float4*)(cbias + 32 * wv + 16 * mt + 4 * quad);
  #pragma unroll
  for (int mt = 0; mt < 2; ++mt)
    #pragma unroll
    for (int nt = 0; nt < 4; ++nt)
      #pragma unroll
      for (int r = 0; r < 4; ++r) {
        int c_out = 32 * wv + 16 * mt + 4 * quad + r;
        OST[c_out][16 * nt + l16] = fmaxf(acc2[mt][nt][r] + ((const float*)&cb4[mt])[r], 0.f);
      }
  __syncthreads();

  // epilogue 2b: coalesced float4 aff reads + out stores
  #pragma unroll
  for (int p = 0; p < 8; ++p) {
    int id = tid + 256 * p; int c = id >> 4; int g = id & 15;
    float4 y = *(const float4*)&OST[c][4 * g];
    size_t ai = (size_t)c * 2048 + n0 + 4 * g;
    float4 aw4 = *(const float4*)(aff_w + ai);
    float4 ab4 = *(const float4*)(aff_b + ai);
    float4 o;
    o.x = y.x * aw4.x + ab4.x + y.x;
    o.y = y.y * aw4.y + ab4.y + y.y;
    o.z = y.z * aw4.z + ab4.z + y.z;
    o.w = y.w * aw4.w + ab4.w + y.w;
    *(float4*)(out + (size_t)(b * 128 + c) * 2048 + n0 + 4 * g) = o;
  }
}

// ---------------------------------------------------------------------------
extern "C" void kernel_launch(void* const* d_in, const int* in_sizes, int n_in,
                              void* d_out, int out_size, void* d_ws, size_t ws_size,
                              hipStream_t stream)
{
  const float* x      = (const float*)d_in[0];
  const float* qw     = (const float*)d_in[1];
  const float* qb     = (const float*)d_in[2];
  const float* vw     = (const float*)d_in[3];
  const float* vb     = (const float*)d_in[4];
  const float* cw     = (const float*)d_in[5];
  const float* cb     = (const float*)d_in[6];
  const float* memory = (const float*)d_in[7];
  const float* nv1    = (const float*)d_in[8];
  const float* nv2    = (const float*)d_in[9];
  const float* wpool  = (const float*)d_in[10];
  const float* bpool  = (const float*)d_in[11];
  const float* aw     = (const float*)d_in[12];
  const float* ab     = (const float*)d_in[13];
  float* out = (float*)d_out;

  char* ws = (char*)d_ws;
  ushort_t* QsT      = (ushort_t*)(ws);                 // 33,554,432 B
  ushort_t* VT       = (ushort_t*)(ws + 33554432);      // 33,554,432 B
  float*    kvws     = (float*)   (ws + 67108864);      //  1,048,576 B
  ushort_t* keysT    = (ushort_t*)(ws + 68157440);      //    524,288 B
  float*    bias_dyn = (float*)   (ws + 69206016);      //    262,144 B
  ushort_t* wqb      = (ushort_t*)(ws + 69468160);      //     32,768 B
  ushort_t* wvb      = (ushort_t*)(ws + 69500928);      //     32,768 B
  ushort_t* wcb      = (ushort_t*)(ws + 69533696);      //     32,768 B
  ushort_t* Ebuf     = (ushort_t*)(ws + 69566464);      //  8,388,608 B (end 77,955,072)
  ushort_t* bpT      = (ushort_t*)(ws + 77955072);      //    131,072 B (end 78,086,144)
  float*    kvp      = (float*)   (ws + 78086144);      // 33,554,432 B (end 111,640,576)

  k0_prep<<<256, 256, 0, stream>>>(qw, vw, cw, memory, bpool, wqb, wvb, wcb,
                                   keysT, bias_dyn, bpT);
  kb1<<<2048, 256, 0, stream>>>(nv1, nv2, Ebuf);
  kb2<<<128, 256, 0, stream>>>(Ebuf, bpT, bias_dyn);
  k1_qv<<<2048, 256, 0, stream>>>(x, wqb, wvb, qb, vb, keysT, QsT, VT, kvp);
  kred<<<256, 256, 0, stream>>>(kvp, kvws);
  k3_out<<<2048, 256, 0, stream>>>(QsT, VT, kvws, bias_dyn, wcb, cb, wpool, aw, ab, out);
}

// Round 8
// 209.032 us; speedup vs baseline: 1.1799x; 1.0326x over previous
//
#include <hip/hip_runtime.h>

#define NB 64
#define CH 128
#define NNODE 2048
#define NH 4
#define DKK 32
#define INVS 0.17677669529663687f

typedef __bf16 bf16x8 __attribute__((ext_vector_type(8)));
typedef float f32x4 __attribute__((ext_vector_type(4)));
typedef unsigned short ushort_t;

union U16x8 { uint4 u; bf16x8 b; unsigned short s[8]; };
union U16x4 { uint2 u; unsigned short s[4]; };

__device__ inline bf16x8 as_bf16x8(uint4 u){ U16x8 x; x.u = u; return x.b; }
__device__ inline unsigned short f2b(float f){ __bf16 h = (__bf16)f; return __builtin_bit_cast(unsigned short, h); }
__device__ inline float b2f(unsigned short u){ __bf16 h = __builtin_bit_cast(__bf16, u); return (float)h; }

// XT XOR swizzle: 16B-granular, row-keyed, bijective. r7: conflicts 4.06M->2.23M.
#define XT_IDX(n, c) ((n) * 136 + ((c) ^ ((((n) >> 2) & 7) << 3)))

// ---------------------------------------------------------------------------
// kA = k0_prep (blocks 0..255) + kb1 (blocks 256..2303). Independent work
// merged into one launch: fewer boundaries, better machine fill.
// ---------------------------------------------------------------------------
__global__ __launch_bounds__(256) void kA(const float* __restrict__ qw,
    const float* __restrict__ vw, const float* __restrict__ cw,
    const float* __restrict__ memory, const float* __restrict__ bias_pool,
    ushort_t* __restrict__ wqb, ushort_t* __restrict__ wvb, ushort_t* __restrict__ wcb,
    ushort_t* __restrict__ keysT, float* __restrict__ bias_dyn,
    ushort_t* __restrict__ bpT,
    const float* __restrict__ nv1, const float* __restrict__ nv2,
    ushort_t* __restrict__ Ebuf)
{
  __shared__ float red[4];
  int tid = threadIdx.x;
  if (blockIdx.x < 256) {
    // ---- k0_prep body ----
    int gid = blockIdx.x * 256 + tid;
    if (gid < 16384) { wqb[gid] = f2b(qw[gid]); wvb[gid] = f2b(vw[gid]); wcb[gid] = f2b(cw[gid]); }
    bias_dyn[gid] = 0.f;                               // 2048*32 = 65536 == 256*256
    { int k = gid >> 11, m = gid & 2047;               // bpT[k][m] = bias_pool[m][k]
      bpT[gid] = f2b(bias_pool[m * 32 + k]); }
    if (gid < 8192) {  // softmax(memory * invscale) -> keysT
      int h = gid >> 11, n = gid & 2047;
      const float* src = memory + (size_t)gid * 32;
      float v[32]; float m = -1e30f;
      #pragma unroll
      for (int i = 0; i < 32; ++i) { v[i] = src[i] * INVS; m = fmaxf(m, v[i]); }
      float s = 0.f;
      #pragma unroll
      for (int i = 0; i < 32; ++i) { v[i] = __expf(v[i] - m); s += v[i]; }
      float inv = 1.f / s;
      #pragma unroll
      for (int i = 0; i < 32; ++i)
        keysT[(size_t)(h * 32 + i) * 2048 + n] = f2b(v[i] * inv);
    }
  } else {
    // ---- kb1 body: row n = blockIdx.x - 256 ----
    int n = blockIdx.x - 256;
    float a1[10];
    #pragma unroll
    for (int d = 0; d < 10; ++d) a1[d] = nv1[n * 10 + d];
    int m0 = tid * 8;
    float s[8];
    #pragma unroll
    for (int j = 0; j < 8; ++j) s[j] = 0.f;
    #pragma unroll
    for (int d = 0; d < 10; ++d) {
      const float* p = nv2 + d * 2048 + m0;
      float4 u = *(const float4*)p; float4 v = *(const float4*)(p + 4);
      s[0] += a1[d] * u.x; s[1] += a1[d] * u.y; s[2] += a1[d] * u.z; s[3] += a1[d] * u.w;
      s[4] += a1[d] * v.x; s[5] += a1[d] * v.y; s[6] += a1[d] * v.z; s[7] += a1[d] * v.w;
    }
    float e[8]; float sum = 0.f;
    #pragma unroll
    for (int j = 0; j < 8; ++j) { e[j] = __expf(fmaxf(s[j], 0.f)); sum += e[j]; }
    #pragma unroll
    for (int d = 1; d < 64; d <<= 1) sum += __shfl_xor(sum, d);
    if ((tid & 63) == 0) red[tid >> 6] = sum;
    __syncthreads();
    float inv = 1.f / (red[0] + red[1] + red[2] + red[3]);
    U16x8 o;
    #pragma unroll
    for (int j = 0; j < 8; ++j) o.s[j] = f2b(e[j] * inv);
    *(uint4*)(Ebuf + (size_t)n * 2048 + m0) = o.u;
  }
}

// ---------------------------------------------------------------------------
// kB = kb2 (blocks 0..127) + k1_qv (blocks 128..2175). kb2 is independent of
// k1; merged it co-executes with k1's 2048 blocks instead of occupying the
// machine at 0.5 block/CU serially.
// k1 v8: two-pass Q/V (r4/r6: merged spills), XT swizzle (r7), all-8-loads-
// upfront staging (MLP), no-max Q softmax (post-relu args in [0,~0.5] — exp
// safe, algebraically identical), fused kv tail with per-block stores (r3).
// ---------------------------------------------------------------------------
__global__ __launch_bounds__(256, 4) void kB(
    const ushort_t* __restrict__ Ebuf, const ushort_t* __restrict__ bpT,
    float* __restrict__ bias_dyn,
    const float* __restrict__ x,
    const ushort_t* __restrict__ wqb, const ushort_t* __restrict__ wvb,
    const float* __restrict__ qbias, const float* __restrict__ vbias,
    const ushort_t* __restrict__ keysT,
    ushort_t* __restrict__ QsT, ushort_t* __restrict__ VT,
    float* __restrict__ kvp)
{
  __shared__ __align__(16) ushort_t XT[64 * 136];   // x^T bf16 (swizzled), later V
  __shared__ __align__(16) ushort_t QO[64][136];    // Q out
  int tid = threadIdx.x; int wv = tid >> 6; int lane = tid & 63;
  int quad = lane >> 4; int l16 = lane & 15;
  f32x4 zero4 = {0.f,0.f,0.f,0.f};

  if (blockIdx.x < 128) {
    // ---- kb2 body: bias_dyn = Ebuf @ bias_pool, 8-way K-split, atomics ----
    int bid = blockIdx.x;
    int n0 = (bid >> 3) * 128;
    int m0 = (bid & 7) * 256;
    int r0 = n0 + 32 * wv;
    f32x4 acc[2][2];
    acc[0][0] = zero4; acc[0][1] = zero4; acc[1][0] = zero4; acc[1][1] = zero4;
    for (int ks = 0; ks < 256; ks += 32) {
      int mb = m0 + ks + 8 * quad;
      bf16x8 a0 = *(const bf16x8*)(Ebuf + (size_t)(r0 + l16) * 2048 + mb);
      bf16x8 a1 = *(const bf16x8*)(Ebuf + (size_t)(r0 + 16 + l16) * 2048 + mb);
      bf16x8 b0 = *(const bf16x8*)(bpT + (size_t)l16 * 2048 + mb);
      bf16x8 b1 = *(const bf16x8*)(bpT + (size_t)(16 + l16) * 2048 + mb);
      acc[0][0] = __builtin_amdgcn_mfma_f32_16x16x32_bf16(a0, b0, acc[0][0], 0, 0, 0);
      acc[0][1] = __builtin_amdgcn_mfma_f32_16x16x32_bf16(a0, b1, acc[0][1], 0, 0, 0);
      acc[1][0] = __builtin_amdgcn_mfma_f32_16x16x32_bf16(a1, b0, acc[1][0], 0, 0, 0);
      acc[1][1] = __builtin_amdgcn_mfma_f32_16x16x32_bf16(a1, b1, acc[1][1], 0, 0, 0);
    }
    #pragma unroll
    for (int rt = 0; rt < 2; ++rt)
      #pragma unroll
      for (int ct = 0; ct < 2; ++ct)
        #pragma unroll
        for (int r = 0; r < 4; ++r)
          atomicAdd(bias_dyn + (size_t)(r0 + 16*rt + 4*quad + r) * 32 + 16*ct + l16,
                    acc[rt][ct][r]);
    return;
  }

  // ---- k1_qv body ----
  int bid = blockIdx.x - 128; int b = bid >> 5; int n0 = (bid & 31) * 64;

  // Q-pass weight frags issued first so they're in flight during staging.
  uint4 wq[2][4];
  #pragma unroll
  for (int ct = 0; ct < 2; ++ct)
    #pragma unroll
    for (int k0 = 0; k0 < 4; ++k0)
      wq[ct][k0] = *(const uint4*)(wqb + (32 * wv + 16 * ct + l16) * 128 + 32 * k0 + 8 * quad);

  // stage x: issue ALL 8 float4 loads, then all LDS writes (max MLP)
  {
    float4 r[8];
    int n4 = 4 * (tid & 15);
    #pragma unroll
    for (int p = 0; p < 2; ++p) {
      int c4 = 4 * ((tid >> 4) + 16 * p);
      #pragma unroll
      for (int j = 0; j < 4; ++j)
        r[4 * p + j] = *(const float4*)(x + (size_t)(b * 128 + c4 + j) * 2048 + n0 + n4);
    }
    #pragma unroll
    for (int p = 0; p < 2; ++p) {
      int c4 = 4 * ((tid >> 4) + 16 * p);
      #pragma unroll
      for (int i = 0; i < 4; ++i) {
        U16x4 w;
        w.s[0] = f2b(((const float*)&r[4 * p + 0])[i]);
        w.s[1] = f2b(((const float*)&r[4 * p + 1])[i]);
        w.s[2] = f2b(((const float*)&r[4 * p + 2])[i]);
        w.s[3] = f2b(((const float*)&r[4 * p + 3])[i]);
        *(uint2*)&XT[XT_IDX(n4 + i, c4)] = w.u;
      }
    }
  }
  __syncthreads();

  // ---- PASS 1: Q = softmax(relu(Wq x + qb) * INVS) -> QO (no max-subtract:
  // post-relu args bounded ~[0,0.5], exp safe, algebraically identical) ----
  {
    float4 qb4[2];
    #pragma unroll
    for (int ct = 0; ct < 2; ++ct)
      qb4[ct] = *(const float4*)(qbias + 32 * wv + 16 * ct + 4 * quad);
    #pragma unroll
    for (int nt = 0; nt < 4; ++nt) {
      f32x4 aq[2]; aq[0] = zero4; aq[1] = zero4;
      #pragma unroll
      for (int k0 = 0; k0 < 4; ++k0) {
        bf16x8 bfrag = *(const bf16x8*)&XT[XT_IDX(16 * nt + l16, 32 * k0 + 8 * quad)];
        aq[0] = __builtin_amdgcn_mfma_f32_16x16x32_bf16(as_bf16x8(wq[0][k0]), bfrag, aq[0], 0, 0, 0);
        aq[1] = __builtin_amdgcn_mfma_f32_16x16x32_bf16(as_bf16x8(wq[1][k0]), bfrag, aq[1], 0, 0, 0);
      }
      float sq[2][4]; float sum = 0.f;
      #pragma unroll
      for (int ct = 0; ct < 2; ++ct)
        #pragma unroll
        for (int r = 0; r < 4; ++r) {
          sq[ct][r] = __expf(fmaxf(aq[ct][r] + ((const float*)&qb4[ct])[r], 0.f) * INVS);
          sum += sq[ct][r];
        }
      sum += __shfl_xor(sum, 16);
      sum += __shfl_xor(sum, 32);
      float inv = 1.f / sum;
      #pragma unroll
      for (int ct = 0; ct < 2; ++ct) {
        U16x4 w;
        #pragma unroll
        for (int r = 0; r < 4; ++r) w.s[r] = f2b(sq[ct][r] * inv);
        *(uint2*)&QO[16 * nt + l16][32 * wv + 16 * ct + 4 * quad] = w.u;
      }
    }
  }

  // ---- PASS 2: V = relu(Wv x + vb), packed bf16 in-register ----
  uint2 vout[4][2];
  {
    uint4 wvw[2][4];
    #pragma unroll
    for (int ct = 0; ct < 2; ++ct)
      #pragma unroll
      for (int k0 = 0; k0 < 4; ++k0)
        wvw[ct][k0] = *(const uint4*)(wvb + (32 * wv + 16 * ct + l16) * 128 + 32 * k0 + 8 * quad);
    float4 vb4[2];
    #pragma unroll
    for (int ct = 0; ct < 2; ++ct)
      vb4[ct] = *(const float4*)(vbias + 32 * wv + 16 * ct + 4 * quad);
    #pragma unroll
    for (int nt = 0; nt < 4; ++nt) {
      f32x4 av[2]; av[0] = zero4; av[1] = zero4;
      #pragma unroll
      for (int k0 = 0; k0 < 4; ++k0) {
        bf16x8 bfrag = *(const bf16x8*)&XT[XT_IDX(16 * nt + l16, 32 * k0 + 8 * quad)];
        av[0] = __builtin_amdgcn_mfma_f32_16x16x32_bf16(as_bf16x8(wvw[0][k0]), bfrag, av[0], 0, 0, 0);
        av[1] = __builtin_amdgcn_mfma_f32_16x16x32_bf16(as_bf16x8(wvw[1][k0]), bfrag, av[1], 0, 0, 0);
      }
      #pragma unroll
      for (int ct = 0; ct < 2; ++ct) {
        U16x4 w;
        #pragma unroll
        for (int r = 0; r < 4; ++r)
          w.s[r] = f2b(fmaxf(av[ct][r] + ((const float*)&vb4[ct])[r], 0.f));
        vout[nt][ct] = w.u;
      }
    }
  }
  __syncthreads();   // all XT x-reads done

  #pragma unroll
  for (int nt = 0; nt < 4; ++nt)
    #pragma unroll
    for (int ct = 0; ct < 2; ++ct)
      *(uint2*)&XT[XT_IDX(16 * nt + l16, 32 * wv + 16 * ct + 4 * quad)] = vout[nt][ct];
  __syncthreads();   // XT now holds V

  // ---- fused kv partial: wave wv = head; per-block stores (no atomics) ----
  {
    f32x4 akv[2][2];
    akv[0][0] = zero4; akv[0][1] = zero4; akv[1][0] = zero4; akv[1][1] = zero4;
    #pragma unroll
    for (int ks = 0; ks < 2; ++ks) {
      const ushort_t* kp = keysT + (size_t)(32 * wv) * 2048 + n0 + 32 * ks + 8 * quad;
      bf16x8 ka0 = *(const bf16x8*)(kp + (size_t)l16 * 2048);
      bf16x8 ka1 = *(const bf16x8*)(kp + (size_t)(16 + l16) * 2048);
      U16x8 v0, v1;
      #pragma unroll
      for (int j = 0; j < 8; ++j) {
        int rowk = 32 * ks + 8 * quad + j;
        v0.s[j] = XT[XT_IDX(rowk, 32 * wv + l16)];
        v1.s[j] = XT[XT_IDX(rowk, 32 * wv + 16 + l16)];
      }
      akv[0][0] = __builtin_amdgcn_mfma_f32_16x16x32_bf16(ka0, v0.b, akv[0][0], 0, 0, 0);
      akv[0][1] = __builtin_amdgcn_mfma_f32_16x16x32_bf16(ka0, v1.b, akv[0][1], 0, 0, 0);
      akv[1][0] = __builtin_amdgcn_mfma_f32_16x16x32_bf16(ka1, v0.b, akv[1][0], 0, 0, 0);
      akv[1][1] = __builtin_amdgcn_mfma_f32_16x16x32_bf16(ka1, v1.b, akv[1][1], 0, 0, 0);
    }
    float* kdst = kvp + (size_t)bid * 4096 + wv * 1024;   // [bid][h][y][x]
    #pragma unroll
    for (int xt = 0; xt < 2; ++xt)
      #pragma unroll
      for (int yt = 0; yt < 2; ++yt)
        #pragma unroll
        for (int r = 0; r < 4; ++r)
          kdst[(16 * yt + l16) * 32 + 16 * xt + 4 * quad + r] = akv[xt][yt][r];
  }

  // coalesced bf16 stores [b][n][128]
  #pragma unroll
  for (int j = 0; j < 4; ++j) {
    int id = tid + 256 * j; int n = id >> 4; int u = id & 15;
    size_t go = (size_t)(b * 2048 + n0 + n) * 128 + 8 * u;
    *(uint4*)(QsT + go) = *(uint4*)&QO[n][8 * u];
    *(uint4*)(VT  + go) = *(uint4*)&XT[XT_IDX(n, 8 * u)];
  }
}

// ---------------------------------------------------------------------------
// kred: kvws[b][i] = sum over 32 node-tile partials, float4 per thread.
// grid 256 x 256 (65536 float4 outputs), coalesced.
// ---------------------------------------------------------------------------
__global__ __launch_bounds__(256) void kred(const float* __restrict__ kvp,
    float* __restrict__ kvws)
{
  int gid = blockIdx.x * 256 + threadIdx.x;   // 65536 float4 outputs
  int b = gid >> 10; int i = gid & 1023;
  const float* p = kvp + (size_t)(b * 32) * 4096 + i * 4;
  float4 s = {0.f,0.f,0.f,0.f};
  #pragma unroll
  for (int t = 0; t < 32; ++t) {
    float4 v = *(const float4*)(p + (size_t)t * 4096);
    s.x += v.x; s.y += v.y; s.z += v.z; s.w += v.w;
  }
  *(float4*)(kvws + (size_t)gid * 4) = s;
}

// ---------------------------------------------------------------------------
// k3_out: attn_qkv (block-diag GEMM, K=32/head) + Ws*V + bias_dyn -> MID(LDS),
// then final conv GEMM + relu + affine residual. Block: 64 nodes of one b.
// Epilogue restages fp32 results through an LDS overlay for coalesced stores.
// ---------------------------------------------------------------------------
__global__ __launch_bounds__(256, 3) void k3_out(const ushort_t* __restrict__ QsT,
    const ushort_t* __restrict__ VT, const float* __restrict__ kvws,
    const float* __restrict__ bias_dyn, const ushort_t* __restrict__ wcb,
    const float* __restrict__ cbias, const float* __restrict__ wpool,
    const float* __restrict__ aff_w, const float* __restrict__ aff_b,
    float* __restrict__ out)
{
  int bid = blockIdx.x; int b = bid >> 5; int n0 = (bid & 31) * 64;
  int tid = threadIdx.x; int wv = tid >> 6; int lane = tid & 63;
  int quad = lane >> 4; int l16 = lane & 15;
  __shared__ __align__(16) char smem[53760];
  ushort_t (*kvT)[32][40] = (ushort_t(*)[32][40])(smem);
  ushort_t (*MID)[136]    = (ushort_t(*)[136])(smem + 10240);
  ushort_t (*VL)[132]     = (ushort_t(*)[132])(smem + 27648);
  float    (*BD)[36]      = (float(*)[36])(smem + 44544);
  float    (*OST)[64]     = (float(*)[64])(smem + 10240);

  float Ws = 0.f;
  #pragma unroll
  for (int i = 0; i < 9; ++i) Ws += wpool[i];

  uint4 wc[2][4];
  #pragma unroll
  for (int mt = 0; mt < 2; ++mt)
    #pragma unroll
    for (int k0 = 0; k0 < 4; ++k0)
      wc[mt][k0] = *(const uint4*)(wcb + (32 * wv + 16 * mt + l16) * 128 + 32 * k0 + 8 * quad);

  #pragma unroll
  for (int p = 0; p < 16; ++p) {
    int id = tid + 256 * p;
    kvT[id >> 10][(id >> 5) & 31][id & 31] = f2b(kvws[(size_t)b * 4096 + id]);
  }
  #pragma unroll
  for (int p = 0; p < 4; ++p) {        // V tile
    int id = tid + 256 * p; int n = id >> 4; int u = id & 15;
    *(uint4*)&VL[n][8 * u] = *(const uint4*)(VT + (size_t)(b * 2048 + n0 + n) * 128 + 8 * u);
  }
  #pragma unroll
  for (int p = 0; p < 2; ++p) {        // bias_dyn tile
    int id = tid + 256 * p; int n = id >> 3; int g = id & 7;
    *(float4*)&BD[n][4 * g] = *(const float4*)(bias_dyn + (size_t)(n0 + n) * 32 + 4 * g);
  }
  __syncthreads();

  f32x4 zero4 = {0.f,0.f,0.f,0.f};
  f32x4 acc1[4][2];
  #pragma unroll
  for (int nt = 0; nt < 4; ++nt) { acc1[nt][0] = zero4; acc1[nt][1] = zero4; }
  #pragma unroll
  for (int nt = 0; nt < 4; ++nt) {
    bf16x8 aq = *(const bf16x8*)(QsT + (size_t)(b * 2048 + n0 + 16 * nt + l16) * 128 + 32 * wv + 8 * quad);
    #pragma unroll
    for (int ct = 0; ct < 2; ++ct)
      acc1[nt][ct] = __builtin_amdgcn_mfma_f32_16x16x32_bf16(
          aq, *(const bf16x8*)&kvT[wv][16 * ct + l16][8 * quad], acc1[nt][ct], 0, 0, 0);
  }

  #pragma unroll
  for (int nt = 0; nt < 4; ++nt)
    #pragma unroll
    for (int ct = 0; ct < 2; ++ct)
      #pragma unroll
      for (int r = 0; r < 4; ++r) {
        int nl = 16 * nt + 4 * quad + r;
        int cc = 32 * wv + 16 * ct + l16;
        float v = b2f(VL[nl][cc]);
        float bd = BD[nl][16 * ct + l16];
        MID[nl][cc] = f2b(acc1[nt][ct][r] + Ws * v + bd);
      }
  __syncthreads();

  f32x4 acc2[2][4];
  #pragma unroll
  for (int mt = 0; mt < 2; ++mt)
    #pragma unroll
    for (int nt = 0; nt < 4; ++nt) acc2[mt][nt] = zero4;
  #pragma unroll
  for (int k0 = 0; k0 < 4; ++k0) {
    bf16x8 bb[4];
    #pragma unroll
    for (int nt = 0; nt < 4; ++nt)
      bb[nt] = *(const bf16x8*)&MID[16 * nt + l16][32 * k0 + 8 * quad];
    #pragma unroll
    for (int mt = 0; mt < 2; ++mt)
      #pragma unroll
      for (int nt = 0; nt < 4; ++nt)
        acc2[mt][nt] = __builtin_amdgcn_mfma_f32_16x16x32_bf16(
            as_bf16x8(wc[mt][k0]), bb[nt], acc2[mt][nt], 0, 0, 0);
  }
  __syncthreads();   // MID reads done; OST may overwrite

  float4 cb4[2];
  #pragma unroll
  for (int mt = 0; mt < 2; ++mt)
    cb4[mt] = *(const float4*)(cbias + 32 * wv + 16 * mt + 4 * quad);
  #pragma unroll
  for (int mt = 0; mt < 2; ++mt)
    #pragma unroll
    for (int nt = 0; nt < 4; ++nt)
      #pragma unroll
      for (int r = 0; r < 4; ++r) {
        int c_out = 32 * wv + 16 * mt + 4 * quad + r;
        OST[c_out][16 * nt + l16] = fmaxf(acc2[mt][nt][r] + ((const float*)&cb4[mt])[r], 0.f);
      }
  __syncthreads();

  #pragma unroll
  for (int p = 0; p < 8; ++p) {
    int id = tid + 256 * p; int c = id >> 4; int g = id & 15;
    float4 y = *(const float4*)&OST[c][4 * g];
    size_t ai = (size_t)c * 2048 + n0 + 4 * g;
    float4 aw4 = *(const float4*)(aff_w + ai);
    float4 ab4 = *(const float4*)(aff_b + ai);
    float4 o;
    o.x = y.x * aw4.x + ab4.x + y.x;
    o.y = y.y * aw4.y + ab4.y + y.y;
    o.z = y.z * aw4.z + ab4.z + y.z;
    o.w = y.w * aw4.w + ab4.w + y.w;
    *(float4*)(out + (size_t)(b * 128 + c) * 2048 + n0 + 4 * g) = o;
  }
}

// ---------------------------------------------------------------------------
extern "C" void kernel_launch(void* const* d_in, const int* in_sizes, int n_in,
                              void* d_out, int out_size, void* d_ws, size_t ws_size,
                              hipStream_t stream)
{
  const float* x      = (const float*)d_in[0];
  const float* qw     = (const float*)d_in[1];
  const float* qb     = (const float*)d_in[2];
  const float* vw     = (const float*)d_in[3];
  const float* vb     = (const float*)d_in[4];
  const float* cw     = (const float*)d_in[5];
  const float* cb     = (const float*)d_in[6];
  const float* memory = (const float*)d_in[7];
  const float* nv1    = (const float*)d_in[8];
  const float* nv2    = (const float*)d_in[9];
  const float* wpool  = (const float*)d_in[10];
  const float* bpool  = (const float*)d_in[11];
  const float* aw     = (const float*)d_in[12];
  const float* ab     = (const float*)d_in[13];
  float* out = (float*)d_out;

  char* ws = (char*)d_ws;
  ushort_t* QsT      = (ushort_t*)(ws);                 // 33,554,432 B
  ushort_t* VT       = (ushort_t*)(ws + 33554432);      // 33,554,432 B
  float*    kvws     = (float*)   (ws + 67108864);      //  1,048,576 B
  ushort_t* keysT    = (ushort_t*)(ws + 68157440);      //    524,288 B
  float*    bias_dyn = (float*)   (ws + 69206016);      //    262,144 B
  ushort_t* wqb      = (ushort_t*)(ws + 69468160);      //     32,768 B
  ushort_t* wvb      = (ushort_t*)(ws + 69500928);      //     32,768 B
  ushort_t* wcb      = (ushort_t*)(ws + 69533696);      //     32,768 B
  ushort_t* Ebuf     = (ushort_t*)(ws + 69566464);      //  8,388,608 B (end 77,955,072)
  ushort_t* bpT      = (ushort_t*)(ws + 77955072);      //    131,072 B (end 78,086,144)
  float*    kvp      = (float*)   (ws + 78086144);      // 33,554,432 B (end 111,640,576)

  kA<<<2304, 256, 0, stream>>>(qw, vw, cw, memory, bpool, wqb, wvb, wcb,
                               keysT, bias_dyn, bpT, nv1, nv2, Ebuf);
  kB<<<2176, 256, 0, stream>>>(Ebuf, bpT, bias_dyn, x, wqb, wvb, qb, vb,
                               keysT, QsT, VT, kvp);
  kred<<<256, 256, 0, stream>>>(kvp, kvws);
  k3_out<<<2048, 256, 0, stream>>>(QsT, VT, kvws, bias_dyn, wcb, cb, wpool, aw, ab, out);
}

// Round 9
// 207.193 us; speedup vs baseline: 1.1904x; 1.0089x over previous
//
#include <hip/hip_runtime.h>

#define NB 64
#define CH 128
#define NNODE 2048
#define NH 4
#define DKK 32
#define INVS 0.17677669529663687f

typedef __bf16 bf16x8 __attribute__((ext_vector_type(8)));
typedef float f32x4 __attribute__((ext_vector_type(4)));
typedef unsigned short ushort_t;

union U16x8 { uint4 u; bf16x8 b; unsigned short s[8]; };
union U16x4 { uint2 u; unsigned short s[4]; };

__device__ inline bf16x8 as_bf16x8(uint4 u){ U16x8 x; x.u = u; return x.b; }
__device__ inline unsigned short f2b(float f){ __bf16 h = (__bf16)f; return __builtin_bit_cast(unsigned short, h); }
__device__ inline float b2f(unsigned short u){ __bf16 h = __builtin_bit_cast(__bf16, u); return (float)h; }

// Shared XOR swizzle for stride-128 [64][128] bf16 LDS tiles. 16B-granular,
// row-keyed, bijective per row; result stays <128 so NO pad column needed
// (this is what buys 5 blocks/CU in kB, 4 in k3). Masks are multiples of 8
// -> all uint2/uint4/b128 accesses stay aligned. Swizzle validated r6/r7.
#define SWZ_IDX(n, c) ((n) * 128 + ((c) ^ ((((n) >> 2) & 7) << 3)))

// ---------------------------------------------------------------------------
// kA = k0_prep (blocks 0..255) + kb1 (blocks 256..2303).
// ---------------------------------------------------------------------------
__global__ __launch_bounds__(256) void kA(const float* __restrict__ qw,
    const float* __restrict__ vw, const float* __restrict__ cw,
    const float* __restrict__ memory, const float* __restrict__ bias_pool,
    ushort_t* __restrict__ wqb, ushort_t* __restrict__ wvb, ushort_t* __restrict__ wcb,
    ushort_t* __restrict__ keysT, float* __restrict__ bias_dyn,
    ushort_t* __restrict__ bpT,
    const float* __restrict__ nv1, const float* __restrict__ nv2,
    ushort_t* __restrict__ Ebuf)
{
  __shared__ float red[4];
  int tid = threadIdx.x;
  if (blockIdx.x < 256) {
    int gid = blockIdx.x * 256 + tid;
    if (gid < 16384) { wqb[gid] = f2b(qw[gid]); wvb[gid] = f2b(vw[gid]); wcb[gid] = f2b(cw[gid]); }
    bias_dyn[gid] = 0.f;
    { int k = gid >> 11, m = gid & 2047;
      bpT[gid] = f2b(bias_pool[m * 32 + k]); }
    if (gid < 8192) {
      int h = gid >> 11, n = gid & 2047;
      const float* src = memory + (size_t)gid * 32;
      float v[32]; float m = -1e30f;
      #pragma unroll
      for (int i = 0; i < 32; ++i) { v[i] = src[i] * INVS; m = fmaxf(m, v[i]); }
      float s = 0.f;
      #pragma unroll
      for (int i = 0; i < 32; ++i) { v[i] = __expf(v[i] - m); s += v[i]; }
      float inv = 1.f / s;
      #pragma unroll
      for (int i = 0; i < 32; ++i)
        keysT[(size_t)(h * 32 + i) * 2048 + n] = f2b(v[i] * inv);
    }
  } else {
    int n = blockIdx.x - 256;
    float a1[10];
    #pragma unroll
    for (int d = 0; d < 10; ++d) a1[d] = nv1[n * 10 + d];
    int m0 = tid * 8;
    float s[8];
    #pragma unroll
    for (int j = 0; j < 8; ++j) s[j] = 0.f;
    #pragma unroll
    for (int d = 0; d < 10; ++d) {
      const float* p = nv2 + d * 2048 + m0;
      float4 u = *(const float4*)p; float4 v = *(const float4*)(p + 4);
      s[0] += a1[d] * u.x; s[1] += a1[d] * u.y; s[2] += a1[d] * u.z; s[3] += a1[d] * u.w;
      s[4] += a1[d] * v.x; s[5] += a1[d] * v.y; s[6] += a1[d] * v.z; s[7] += a1[d] * v.w;
    }
    float e[8]; float sum = 0.f;
    #pragma unroll
    for (int j = 0; j < 8; ++j) { e[j] = __expf(fmaxf(s[j], 0.f)); sum += e[j]; }
    #pragma unroll
    for (int d = 1; d < 64; d <<= 1) sum += __shfl_xor(sum, d);
    if ((tid & 63) == 0) red[tid >> 6] = sum;
    __syncthreads();
    float inv = 1.f / (red[0] + red[1] + red[2] + red[3]);
    U16x8 o;
    #pragma unroll
    for (int j = 0; j < 8; ++j) o.s[j] = f2b(e[j] * inv);
    *(uint4*)(Ebuf + (size_t)n * 2048 + m0) = o.u;
  }
}

// ---------------------------------------------------------------------------
// kB = kb2 (blocks 0..127) + k1_qv (blocks 128..2175).
// v9: XT/QO at stride 128 + shared swizzle -> LDS 32768 B = 5 blocks/CU
// (was 34816 = 4). launch_bounds(256,5): VGPR budget 102 >= measured 56.
// Two-pass Q/V (r4/r6: merged spills), fused kv tail per-block stores (r3).
// ---------------------------------------------------------------------------
__global__ __launch_bounds__(256, 5) void kB(
    const ushort_t* __restrict__ Ebuf, const ushort_t* __restrict__ bpT,
    float* __restrict__ bias_dyn,
    const float* __restrict__ x,
    const ushort_t* __restrict__ wqb, const ushort_t* __restrict__ wvb,
    const float* __restrict__ qbias, const float* __restrict__ vbias,
    const ushort_t* __restrict__ keysT,
    ushort_t* __restrict__ QsT, ushort_t* __restrict__ VT,
    float* __restrict__ kvp)
{
  __shared__ __align__(16) ushort_t XT[64 * 128];   // x^T bf16 (swizzled), later V
  __shared__ __align__(16) ushort_t QO[64 * 128];   // Q out (swizzled)
  int tid = threadIdx.x; int wv = tid >> 6; int lane = tid & 63;
  int quad = lane >> 4; int l16 = lane & 15;
  f32x4 zero4 = {0.f,0.f,0.f,0.f};

  if (blockIdx.x < 128) {
    // ---- kb2 body ----
    int bid = blockIdx.x;
    int n0 = (bid >> 3) * 128;
    int m0 = (bid & 7) * 256;
    int r0 = n0 + 32 * wv;
    f32x4 acc[2][2];
    acc[0][0] = zero4; acc[0][1] = zero4; acc[1][0] = zero4; acc[1][1] = zero4;
    for (int ks = 0; ks < 256; ks += 32) {
      int mb = m0 + ks + 8 * quad;
      bf16x8 a0 = *(const bf16x8*)(Ebuf + (size_t)(r0 + l16) * 2048 + mb);
      bf16x8 a1 = *(const bf16x8*)(Ebuf + (size_t)(r0 + 16 + l16) * 2048 + mb);
      bf16x8 b0 = *(const bf16x8*)(bpT + (size_t)l16 * 2048 + mb);
      bf16x8 b1 = *(const bf16x8*)(bpT + (size_t)(16 + l16) * 2048 + mb);
      acc[0][0] = __builtin_amdgcn_mfma_f32_16x16x32_bf16(a0, b0, acc[0][0], 0, 0, 0);
      acc[0][1] = __builtin_amdgcn_mfma_f32_16x16x32_bf16(a0, b1, acc[0][1], 0, 0, 0);
      acc[1][0] = __builtin_amdgcn_mfma_f32_16x16x32_bf16(a1, b0, acc[1][0], 0, 0, 0);
      acc[1][1] = __builtin_amdgcn_mfma_f32_16x16x32_bf16(a1, b1, acc[1][1], 0, 0, 0);
    }
    #pragma unroll
    for (int rt = 0; rt < 2; ++rt)
      #pragma unroll
      for (int ct = 0; ct < 2; ++ct)
        #pragma unroll
        for (int r = 0; r < 4; ++r)
          atomicAdd(bias_dyn + (size_t)(r0 + 16*rt + 4*quad + r) * 32 + 16*ct + l16,
                    acc[rt][ct][r]);
    return;
  }

  // ---- k1_qv body ----
  int bid = blockIdx.x - 128; int b = bid >> 5; int n0 = (bid & 31) * 64;

  uint4 wq[2][4];
  #pragma unroll
  for (int ct = 0; ct < 2; ++ct)
    #pragma unroll
    for (int k0 = 0; k0 < 4; ++k0)
      wq[ct][k0] = *(const uint4*)(wqb + (32 * wv + 16 * ct + l16) * 128 + 32 * k0 + 8 * quad);

  // stage x: issue ALL 8 float4 loads, then all LDS writes
  {
    float4 r[8];
    int n4 = 4 * (tid & 15);
    #pragma unroll
    for (int p = 0; p < 2; ++p) {
      int c4 = 4 * ((tid >> 4) + 16 * p);
      #pragma unroll
      for (int j = 0; j < 4; ++j)
        r[4 * p + j] = *(const float4*)(x + (size_t)(b * 128 + c4 + j) * 2048 + n0 + n4);
    }
    #pragma unroll
    for (int p = 0; p < 2; ++p) {
      int c4 = 4 * ((tid >> 4) + 16 * p);
      #pragma unroll
      for (int i = 0; i < 4; ++i) {
        U16x4 w;
        w.s[0] = f2b(((const float*)&r[4 * p + 0])[i]);
        w.s[1] = f2b(((const float*)&r[4 * p + 1])[i]);
        w.s[2] = f2b(((const float*)&r[4 * p + 2])[i]);
        w.s[3] = f2b(((const float*)&r[4 * p + 3])[i]);
        *(uint2*)&XT[SWZ_IDX(n4 + i, c4)] = w.u;
      }
    }
  }
  __syncthreads();

  // ---- PASS 1: Q = softmax(relu(Wq x + qb) * INVS) -> QO (no max-subtract) ----
  {
    float4 qb4[2];
    #pragma unroll
    for (int ct = 0; ct < 2; ++ct)
      qb4[ct] = *(const float4*)(qbias + 32 * wv + 16 * ct + 4 * quad);
    #pragma unroll
    for (int nt = 0; nt < 4; ++nt) {
      f32x4 aq[2]; aq[0] = zero4; aq[1] = zero4;
      #pragma unroll
      for (int k0 = 0; k0 < 4; ++k0) {
        bf16x8 bfrag = *(const bf16x8*)&XT[SWZ_IDX(16 * nt + l16, 32 * k0 + 8 * quad)];
        aq[0] = __builtin_amdgcn_mfma_f32_16x16x32_bf16(as_bf16x8(wq[0][k0]), bfrag, aq[0], 0, 0, 0);
        aq[1] = __builtin_amdgcn_mfma_f32_16x16x32_bf16(as_bf16x8(wq[1][k0]), bfrag, aq[1], 0, 0, 0);
      }
      float sq[2][4]; float sum = 0.f;
      #pragma unroll
      for (int ct = 0; ct < 2; ++ct)
        #pragma unroll
        for (int r = 0; r < 4; ++r) {
          sq[ct][r] = __expf(fmaxf(aq[ct][r] + ((const float*)&qb4[ct])[r], 0.f) * INVS);
          sum += sq[ct][r];
        }
      sum += __shfl_xor(sum, 16);
      sum += __shfl_xor(sum, 32);
      float inv = 1.f / sum;
      #pragma unroll
      for (int ct = 0; ct < 2; ++ct) {
        U16x4 w;
        #pragma unroll
        for (int r = 0; r < 4; ++r) w.s[r] = f2b(sq[ct][r] * inv);
        *(uint2*)&QO[SWZ_IDX(16 * nt + l16, 32 * wv + 16 * ct + 4 * quad)] = w.u;
      }
    }
  }

  // ---- PASS 2: V = relu(Wv x + vb), packed bf16 in-register ----
  uint2 vout[4][2];
  {
    uint4 wvw[2][4];
    #pragma unroll
    for (int ct = 0; ct < 2; ++ct)
      #pragma unroll
      for (int k0 = 0; k0 < 4; ++k0)
        wvw[ct][k0] = *(const uint4*)(wvb + (32 * wv + 16 * ct + l16) * 128 + 32 * k0 + 8 * quad);
    float4 vb4[2];
    #pragma unroll
    for (int ct = 0; ct < 2; ++ct)
      vb4[ct] = *(const float4*)(vbias + 32 * wv + 16 * ct + 4 * quad);
    #pragma unroll
    for (int nt = 0; nt < 4; ++nt) {
      f32x4 av[2]; av[0] = zero4; av[1] = zero4;
      #pragma unroll
      for (int k0 = 0; k0 < 4; ++k0) {
        bf16x8 bfrag = *(const bf16x8*)&XT[SWZ_IDX(16 * nt + l16, 32 * k0 + 8 * quad)];
        av[0] = __builtin_amdgcn_mfma_f32_16x16x32_bf16(as_bf16x8(wvw[0][k0]), bfrag, av[0], 0, 0, 0);
        av[1] = __builtin_amdgcn_mfma_f32_16x16x32_bf16(as_bf16x8(wvw[1][k0]), bfrag, av[1], 0, 0, 0);
      }
      #pragma unroll
      for (int ct = 0; ct < 2; ++ct) {
        U16x4 w;
        #pragma unroll
        for (int r = 0; r < 4; ++r)
          w.s[r] = f2b(fmaxf(av[ct][r] + ((const float*)&vb4[ct])[r], 0.f));
        vout[nt][ct] = w.u;
      }
    }
  }
  __syncthreads();   // all XT x-reads done

  #pragma unroll
  for (int nt = 0; nt < 4; ++nt)
    #pragma unroll
    for (int ct = 0; ct < 2; ++ct)
      *(uint2*)&XT[SWZ_IDX(16 * nt + l16, 32 * wv + 16 * ct + 4 * quad)] = vout[nt][ct];
  __syncthreads();   // XT now holds V

  // ---- fused kv partial: per-block stores ----
  {
    f32x4 akv[2][2];
    akv[0][0] = zero4; akv[0][1] = zero4; akv[1][0] = zero4; akv[1][1] = zero4;
    #pragma unroll
    for (int ks = 0; ks < 2; ++ks) {
      const ushort_t* kp = keysT + (size_t)(32 * wv) * 2048 + n0 + 32 * ks + 8 * quad;
      bf16x8 ka0 = *(const bf16x8*)(kp + (size_t)l16 * 2048);
      bf16x8 ka1 = *(const bf16x8*)(kp + (size_t)(16 + l16) * 2048);
      U16x8 v0, v1;
      #pragma unroll
      for (int j = 0; j < 8; ++j) {
        int rowk = 32 * ks + 8 * quad + j;
        v0.s[j] = XT[SWZ_IDX(rowk, 32 * wv + l16)];
        v1.s[j] = XT[SWZ_IDX(rowk, 32 * wv + 16 + l16)];
      }
      akv[0][0] = __builtin_amdgcn_mfma_f32_16x16x32_bf16(ka0, v0.b, akv[0][0], 0, 0, 0);
      akv[0][1] = __builtin_amdgcn_mfma_f32_16x16x32_bf16(ka0, v1.b, akv[0][1], 0, 0, 0);
      akv[1][0] = __builtin_amdgcn_mfma_f32_16x16x32_bf16(ka1, v0.b, akv[1][0], 0, 0, 0);
      akv[1][1] = __builtin_amdgcn_mfma_f32_16x16x32_bf16(ka1, v1.b, akv[1][1], 0, 0, 0);
    }
    float* kdst = kvp + (size_t)bid * 4096 + wv * 1024;   // [bid][h][y][x]
    #pragma unroll
    for (int xt = 0; xt < 2; ++xt)
      #pragma unroll
      for (int yt = 0; yt < 2; ++yt)
        #pragma unroll
        for (int r = 0; r < 4; ++r)
          kdst[(16 * yt + l16) * 32 + 16 * xt + 4 * quad + r] = akv[xt][yt][r];
  }

  // coalesced bf16 stores [b][n][128]
  #pragma unroll
  for (int j = 0; j < 4; ++j) {
    int id = tid + 256 * j; int n = id >> 4; int u = id & 15;
    size_t go = (size_t)(b * 2048 + n0 + n) * 128 + 8 * u;
    *(uint4*)(QsT + go) = *(uint4*)&QO[SWZ_IDX(n, 8 * u)];
    *(uint4*)(VT  + go) = *(uint4*)&XT[SWZ_IDX(n, 8 * u)];
  }
}

// ---------------------------------------------------------------------------
// kred: kvws[b][i] = sum over 32 node-tile partials, float4 per thread.
// ---------------------------------------------------------------------------
__global__ __launch_bounds__(256) void kred(const float* __restrict__ kvp,
    float* __restrict__ kvws)
{
  int gid = blockIdx.x * 256 + threadIdx.x;   // 65536 float4 outputs
  int b = gid >> 10; int i = gid & 1023;
  const float* p = kvp + (size_t)(b * 32) * 4096 + i * 4;
  float4 s = {0.f,0.f,0.f,0.f};
  #pragma unroll
  for (int t = 0; t < 32; ++t) {
    float4 v = *(const float4*)(p + (size_t)t * 4096);
    s.x += v.x; s.y += v.y; s.z += v.z; s.w += v.w;
  }
  *(float4*)(kvws + (size_t)gid * 4) = s;
}

// ---------------------------------------------------------------------------
// k3_out v9: LDS 53760 -> 37888 B = 4 blocks/CU (was 3).
//  - kvT LDS + 16-iter staging loop DELETED: each wave loads its head's kv
//    slice from L2-resident kvws as 4 coalesced float4 and converts in-reg
//    (same f2b rounding as before).
//  - MID/VL stride 128 + swizzle; BD stored bf16 [64][40] (added into a
//    bf16-rounded MID anyway).
//  - QsT frags hoisted to 4 early uint4 loads; wc loaded after GEMM1 to cap
//    live regs under the (256,4) 128-VGPR budget.
// Layout: MID @0 (16384) | VL @16384 (16384) | BD @32768 (5120);
//         OST [128][64] f32 @0 (32768) overlays MID+VL after GEMM2.
// ---------------------------------------------------------------------------
__global__ __launch_bounds__(256, 4) void k3_out(const ushort_t* __restrict__ QsT,
    const ushort_t* __restrict__ VT, const float* __restrict__ kvws,
    const float* __restrict__ bias_dyn, const ushort_t* __restrict__ wcb,
    const float* __restrict__ cbias, const float* __restrict__ wpool,
    const float* __restrict__ aff_w, const float* __restrict__ aff_b,
    float* __restrict__ out)
{
  int bid = blockIdx.x; int b = bid >> 5; int n0 = (bid & 31) * 64;
  int tid = threadIdx.x; int wv = tid >> 6; int lane = tid & 63;
  int quad = lane >> 4; int l16 = lane & 15;
  __shared__ __align__(16) char smem[37888];
  ushort_t* MID = (ushort_t*)smem;                      // [64][128] swizzled
  ushort_t* VL  = (ushort_t*)(smem + 16384);            // [64][128] swizzled
  ushort_t (*BD)[40] = (ushort_t(*)[40])(smem + 32768); // bf16, stride 40
  float    (*OST)[64] = (float(*)[64])smem;             // overlay after GEMM2

  // early: kv slice (this wave's head) + Q fragments, all in flight ASAP
  float4 kvlo[2], kvhi[2];
  #pragma unroll
  for (int ct = 0; ct < 2; ++ct) {
    const float* kp = kvws + (size_t)b * 4096 + wv * 1024 + (16 * ct + l16) * 32 + 8 * quad;
    kvlo[ct] = *(const float4*)kp;
    kvhi[ct] = *(const float4*)(kp + 4);
  }
  uint4 aqv[4];
  #pragma unroll
  for (int nt = 0; nt < 4; ++nt)
    aqv[nt] = *(const uint4*)(QsT + (size_t)(b * 2048 + n0 + 16 * nt + l16) * 128 + 32 * wv + 8 * quad);

  float Ws = 0.f;
  #pragma unroll
  for (int i = 0; i < 9; ++i) Ws += wpool[i];

  #pragma unroll
  for (int p = 0; p < 4; ++p) {        // V tile -> VL (swizzled)
    int id = tid + 256 * p; int n = id >> 4; int u = id & 15;
    *(uint4*)&VL[SWZ_IDX(n, 8 * u)] =
        *(const uint4*)(VT + (size_t)(b * 2048 + n0 + n) * 128 + 8 * u);
  }
  #pragma unroll
  for (int p = 0; p < 2; ++p) {        // bias_dyn tile -> BD bf16
    int id = tid + 256 * p; int n = id >> 3; int g = id & 7;
    float4 v = *(const float4*)(bias_dyn + (size_t)(n0 + n) * 32 + 4 * g);
    U16x4 w;
    w.s[0] = f2b(v.x); w.s[1] = f2b(v.y); w.s[2] = f2b(v.z); w.s[3] = f2b(v.w);
    *(uint2*)&BD[n][4 * g] = w.u;
  }
  // kv fp32 -> bf16 fragments (identical rounding to old kvT path)
  U16x8 kf[2];
  #pragma unroll
  for (int ct = 0; ct < 2; ++ct)
    #pragma unroll
    for (int j = 0; j < 4; ++j) {
      kf[ct].s[j]     = f2b(((const float*)&kvlo[ct])[j]);
      kf[ct].s[4 + j] = f2b(((const float*)&kvhi[ct])[j]);
    }
  __syncthreads();

  f32x4 zero4 = {0.f,0.f,0.f,0.f};
  f32x4 acc1[4][2];
  #pragma unroll
  for (int nt = 0; nt < 4; ++nt) { acc1[nt][0] = zero4; acc1[nt][1] = zero4; }
  #pragma unroll
  for (int nt = 0; nt < 4; ++nt)
    #pragma unroll
    for (int ct = 0; ct < 2; ++ct)
      acc1[nt][ct] = __builtin_amdgcn_mfma_f32_16x16x32_bf16(
          as_bf16x8(aqv[nt]), kf[ct].b, acc1[nt][ct], 0, 0, 0);

  // wc loads issued here: in flight during epilogue 1, live only for GEMM2
  uint4 wc[2][4];
  #pragma unroll
  for (int mt = 0; mt < 2; ++mt)
    #pragma unroll
    for (int k0 = 0; k0 < 4; ++k0)
      wc[mt][k0] = *(const uint4*)(wcb + (32 * wv + 16 * mt + l16) * 128 + 32 * k0 + 8 * quad);

  // epilogue 1: MID = attn_qkv + Ws*V + bias_dyn (bf16, swizzled)
  #pragma unroll
  for (int nt = 0; nt < 4; ++nt)
    #pragma unroll
    for (int ct = 0; ct < 2; ++ct)
      #pragma unroll
      for (int r = 0; r < 4; ++r) {
        int nl = 16 * nt + 4 * quad + r;
        int cc = 32 * wv + 16 * ct + l16;
        float v = b2f(VL[SWZ_IDX(nl, cc)]);
        float bd = b2f(BD[nl][16 * ct + l16]);
        MID[SWZ_IDX(nl, cc)] = f2b(acc1[nt][ct][r] + Ws * v + bd);
      }
  __syncthreads();

  f32x4 acc2[2][4];
  #pragma unroll
  for (int mt = 0; mt < 2; ++mt)
    #pragma unroll
    for (int nt = 0; nt < 4; ++nt) acc2[mt][nt] = zero4;
  #pragma unroll
  for (int k0 = 0; k0 < 4; ++k0) {
    bf16x8 bb[4];
    #pragma unroll
    for (int nt = 0; nt < 4; ++nt)
      bb[nt] = *(const bf16x8*)&MID[SWZ_IDX(16 * nt + l16, 32 * k0 + 8 * quad)];
    #pragma unroll
    for (int mt = 0; mt < 2; ++mt)
      #pragma unroll
      for (int nt = 0; nt < 4; ++nt)
        acc2[mt][nt] = __builtin_amdgcn_mfma_f32_16x16x32_bf16(
            as_bf16x8(wc[mt][k0]), bb[nt], acc2[mt][nt], 0, 0, 0);
  }
  __syncthreads();   // MID+VL reads done; OST may overwrite

  float4 cb4[2];
  #pragma unroll
  for (int mt = 0; mt < 2; ++mt)
    cb4[mt] = *(const float4*)(cbias + 32 * wv + 16 * mt + 4 * quad);
  #pragma unroll
  for (int mt = 0; mt < 2; ++mt)
    #pragma unroll
    for (int nt = 0; nt < 4; ++nt)
      #pragma unroll
      for (int r = 0; r < 4; ++r) {
        int c_out = 32 * wv + 16 * mt + 4 * quad + r;
        OST[c_out][16 * nt + l16] = fmaxf(acc2[mt][nt][r] + ((const float*)&cb4[mt])[r], 0.f);
      }
  __syncthreads();

  #pragma unroll
  for (int p = 0; p < 8; ++p) {
    int id = tid + 256 * p; int c = id >> 4; int g = id & 15;
    float4 y = *(const float4*)&OST[c][4 * g];
    size_t ai = (size_t)c * 2048 + n0 + 4 * g;
    float4 aw4 = *(const float4*)(aff_w + ai);
    float4 ab4 = *(const float4*)(aff_b + ai);
    float4 o;
    o.x = y.x * aw4.x + ab4.x + y.x;
    o.y = y.y * aw4.y + ab4.y + y.y;
    o.z = y.z * aw4.z + ab4.z + y.z;
    o.w = y.w * aw4.w + ab4.w + y.w;
    *(float4*)(out + (size_t)(b * 128 + c) * 2048 + n0 + 4 * g) = o;
  }
}

// ---------------------------------------------------------------------------
extern "C" void kernel_launch(void* const* d_in, const int* in_sizes, int n_in,
                              void* d_out, int out_size, void* d_ws, size_t ws_size,
                              hipStream_t stream)
{
  const float* x      = (const float*)d_in[0];
  const float* qw     = (const float*)d_in[1];
  const float* qb     = (const float*)d_in[2];
  const float* vw     = (const float*)d_in[3];
  const float* vb     = (const float*)d_in[4];
  const float* cw     = (const float*)d_in[5];
  const float* cb     = (const float*)d_in[6];
  const float* memory = (const float*)d_in[7];
  const float* nv1    = (const float*)d_in[8];
  const float* nv2    = (const float*)d_in[9];
  const float* wpool  = (const float*)d_in[10];
  const float* bpool  = (const float*)d_in[11];
  const float* aw     = (const float*)d_in[12];
  const float* ab     = (const float*)d_in[13];
  float* out = (float*)d_out;

  char* ws = (char*)d_ws;
  ushort_t* QsT      = (ushort_t*)(ws);                 // 33,554,432 B
  ushort_t* VT       = (ushort_t*)(ws + 33554432);      // 33,554,432 B
  float*    kvws     = (float*)   (ws + 67108864);      //  1,048,576 B
  ushort_t* keysT    = (ushort_t*)(ws + 68157440);      //    524,288 B
  float*    bias_dyn = (float*)   (ws + 69206016);      //    262,144 B
  ushort_t* wqb      = (ushort_t*)(ws + 69468160);      //     32,768 B
  ushort_t* wvb      = (ushort_t*)(ws + 69500928);      //     32,768 B
  ushort_t* wcb      = (ushort_t*)(ws + 69533696);      //     32,768 B
  ushort_t* Ebuf     = (ushort_t*)(ws + 69566464);      //  8,388,608 B (end 77,955,072)
  ushort_t* bpT      = (ushort_t*)(ws + 77955072);      //    131,072 B (end 78,086,144)
  float*    kvp      = (float*)   (ws + 78086144);      // 33,554,432 B (end 111,640,576)

  kA<<<2304, 256, 0, stream>>>(qw, vw, cw, memory, bpool, wqb, wvb, wcb,
                               keysT, bias_dyn, bpT, nv1, nv2, Ebuf);
  kB<<<2176, 256, 0, stream>>>(Ebuf, bpT, bias_dyn, x, wqb, wvb, qb, vb,
                               keysT, QsT, VT, kvp);
  kred<<<256, 256, 0, stream>>>(kvp, kvws);
  k3_out<<<2048, 256, 0, stream>>>(QsT, VT, kvws, bias_dyn, wcb, cb, wpool, aw, ab, out);
}